// Round 10
// baseline (3834.859 us; speedup 1.0000x reference)
//
#include <hip/hip_runtime.h>
#include <math.h>

#define B  128
#define L  196
#define F2 512
#define T  32
#define D  256
#define H  512
#define H4 2048
#define KCAT 1280
#define KS 4
#define KCHUNK 320   // KCAT/KS

typedef __attribute__((ext_vector_type(8))) short bf16x8;
typedef __attribute__((ext_vector_type(4))) float f32x4;

__device__ __forceinline__ float sigf(float x) { return 1.0f / (1.0f + expf(-x)); }
__device__ __forceinline__ unsigned short f2bf(float x) {
    unsigned u = __float_as_uint(x);
    u += 0x7FFF + ((u >> 16) & 1);
    return (unsigned short)(u >> 16);
}
__device__ __forceinline__ float bf2f(unsigned short s) {
    return __uint_as_float(((unsigned)s) << 16);
}
__device__ __forceinline__ float wred_sum(float v) {
    for (int o = 32; o > 0; o >>= 1) v += __shfl_down(v, o);
    return v;
}
__device__ __forceinline__ float wred_max(float v) {
    for (int o = 32; o > 0; o >>= 1) v = fmaxf(v, __shfl_down(v, o));
    return v;
}

// ---------- setup (all verified) ----------

__global__ void k_prep2(const float* __restrict__ X, const float* __restrict__ w_a,
                        const float* __restrict__ b_a, unsigned short* __restrict__ Xb,
                        float* __restrict__ fscore, float* __restrict__ fmpart) {
    __shared__ float sp[8][512];
    int b = blockIdx.x, g = blockIdx.y, tid = threadIdx.x;
    int rowi = tid >> 5, lane32 = tid & 31;
    int f0 = tid * 2;
    float2 acc = make_float2(0.f, 0.f);
    for (int s = 0; s < 4; ++s) {
        int li = s * 8 + rowi;
        float4 part[4];
        if (li < 28) {
            size_t row = (size_t)b * L + g * 28 + li;
            const float* src = X + row * F2;
            unsigned short* dst = Xb + row * F2;
            float sc = 0.f;
            #pragma unroll
            for (int j = 0; j < 4; ++j) {
                int f = j * 128 + lane32 * 4;
                float4 v = *(const float4*)(src + f);
                float4 w = *(const float4*)(w_a + f);
                sc += v.x * w.x + v.y * w.y + v.z * w.z + v.w * w.w;
                part[j] = v;
                ushort4 u;
                u.x = f2bf(v.x); u.y = f2bf(v.y); u.z = f2bf(v.z); u.w = f2bf(v.w);
                *(ushort4*)(dst + f) = u;
            }
            for (int o = 16; o > 0; o >>= 1) sc += __shfl_down(sc, o, 32);
            if (lane32 == 0) fscore[row] = sc + b_a[0];
        } else {
            #pragma unroll
            for (int j = 0; j < 4; ++j) part[j] = make_float4(0.f, 0.f, 0.f, 0.f);
        }
        __syncthreads();
        #pragma unroll
        for (int j = 0; j < 4; ++j)
            *(float4*)&sp[rowi][j * 128 + lane32 * 4] = part[j];
        __syncthreads();
        #pragma unroll
        for (int r = 0; r < 8; ++r) { acc.x += sp[r][f0]; acc.y += sp[r][f0 + 1]; }
    }
    *(float2*)&fmpart[((size_t)b * 7 + g) * 512 + f0] = acc;
}

// reduce 7 mean-partials -> bf16 fm; also zero the step-loop sync counters.
__global__ void k_mred(const float* __restrict__ fmpart, unsigned short* __restrict__ fmb,
                       unsigned* __restrict__ cnts) {
    int b = blockIdx.x, tid = threadIdx.x;
    if (b == 0 && tid < 40) cnts[tid] = 0u;
    int f0 = tid * 2;
    float2 acc = make_float2(0.f, 0.f);
    #pragma unroll
    for (int g = 0; g < 7; ++g) {
        float2 v = *(const float2*)&fmpart[((size_t)b * 7 + g) * 512 + f0];
        acc.x += v.x; acc.y += v.y;
    }
    ushort2 u; u.x = f2bf(acc.x * (1.0f / L)); u.y = f2bf(acc.y * (1.0f / L));
    *(ushort2*)(fmb + (size_t)b * F2 + f0) = u;
}

__global__ void k_castw(const float* __restrict__ src, unsigned short* __restrict__ dst) {
    size_t i = ((size_t)blockIdx.x * 256 + threadIdx.x) * 8;
    float4 v0 = *(const float4*)(src + i);
    float4 v1 = *(const float4*)(src + i + 4);
    ushort4 u0, u1;
    u0.x = f2bf(v0.x); u0.y = f2bf(v0.y); u0.z = f2bf(v0.z); u0.w = f2bf(v0.w);
    u1.x = f2bf(v1.x); u1.y = f2bf(v1.y); u1.z = f2bf(v1.z); u1.w = f2bf(v1.w);
    *(ushort4*)(dst + i) = u0;
    *(ushort4*)(dst + i + 4) = u1;
}

__global__ void k_trW(const float* __restrict__ k_w, const float* __restrict__ r_w,
                      unsigned short* __restrict__ WcatT) {
    int job = blockIdx.z;
    if (job == 2 && blockIdx.x >= 8) return;
    const float* src; int colOff;
    if (job == 0)      { src = k_w + (size_t)256 * H4; colOff = 0; }
    else if (job == 1) { src = r_w;                    colOff = 512; }
    else               { src = k_w;                    colOff = 1024; }
    __shared__ float Ls[32][65];
    int r0 = blockIdx.x * 32, c0 = blockIdx.y * 64;
    int tid = threadIdx.x;
    int r = tid >> 3, c8 = (tid & 7) * 8;
    const float* s = src + (size_t)(r0 + r) * H4 + c0 + c8;
    #pragma unroll
    for (int j = 0; j < 8; ++j) Ls[r][c8 + j] = s[j];
    __syncthreads();
    int cc = tid >> 2, q = tid & 3;
    unsigned short tmp[8];
    #pragma unroll
    for (int j = 0; j < 8; ++j) tmp[j] = f2bf(Ls[q * 8 + j][cc]);
    *(float4*)(WcatT + (size_t)(c0 + cc) * KCAT + colOff + r0 + q * 8) = *(float4*)tmp;
}

__global__ void k_trI(const float* __restrict__ w_h, const float* __restrict__ w_c,
                      unsigned short* __restrict__ wiT) {
    int job = blockIdx.z;
    const float* src = job ? w_c : w_h;
    unsigned short* dst = wiT + (size_t)job * 512 * 512;
    __shared__ float Ls[32][65];
    int r0 = blockIdx.x * 32, c0 = blockIdx.y * 64;
    int tid = threadIdx.x;
    int r = tid >> 3, c8 = (tid & 7) * 8;
    const float* s = src + (size_t)(r0 + r) * 512 + c0 + c8;
    #pragma unroll
    for (int j = 0; j < 8; ++j) Ls[r][c8 + j] = s[j];
    __syncthreads();
    int cc = tid >> 2, q = tid & 3;
    unsigned short tmp[8];
    #pragma unroll
    for (int j = 0; j < 8; ++j) tmp[j] = f2bf(Ls[q * 8 + j][cc]);
    *(float4*)(dst + (size_t)(c0 + cc) * 512 + r0 + q * 8) = *(float4*)tmp;
}

// ---------- init-state GEMM (MFMA, verified) ----------
__global__ __launch_bounds__(256) void k_init_gemm(
    const unsigned short* __restrict__ A, const unsigned short* __restrict__ Bt,
    const float* __restrict__ b_h, const float* __restrict__ b_c,
    unsigned short* __restrict__ Abuf0, float* __restrict__ cbuf) {
    __shared__ short As[128 * 64];
    __shared__ short Bs[128 * 64];
    int tid = threadIdx.x;
    int nbase = blockIdx.x * 128;
    int wave = tid >> 6, lane = tid & 63;
    int wm = (wave >> 1) * 64, wn = (wave & 1) * 64;
    int l15 = lane & 15, l4 = lane >> 4;

    f32x4 acc[4][4];
    #pragma unroll
    for (int i = 0; i < 4; ++i)
        #pragma unroll
        for (int j = 0; j < 4; ++j) acc[i][j] = (f32x4){0.f, 0.f, 0.f, 0.f};

    for (int it = 0; it < 8; ++it) {
        int kbase = it * 64;
        #pragma unroll
        for (int ch = 0; ch < 4; ++ch) {
            int idx = ch * 256 + tid;
            int row = idx >> 3, q = idx & 7;
            int k = kbase + q * 8;
            float4 v = *(const float4*)(A + (size_t)row * 512 + k);
            *(float4*)&As[row * 64 + ((q ^ (row & 7)) << 3)] = v;
            float4 w = *(const float4*)(Bt + (size_t)(nbase + row) * 512 + k);
            *(float4*)&Bs[row * 64 + ((q ^ (row & 7)) << 3)] = w;
        }
        __syncthreads();
        #pragma unroll
        for (int ks = 0; ks < 2; ++ks) {
            bf16x8 a[4], b[4];
            #pragma unroll
            for (int f = 0; f < 4; ++f) {
                int ar = wm + f * 16 + l15;
                int q = ks * 4 + l4;
                a[f] = *(const bf16x8*)&As[ar * 64 + ((q ^ (ar & 7)) << 3)];
                int br = wn + f * 16 + l15;
                b[f] = *(const bf16x8*)&Bs[br * 64 + ((q ^ (br & 7)) << 3)];
            }
            #pragma unroll
            for (int fm = 0; fm < 4; ++fm)
                #pragma unroll
                for (int fn = 0; fn < 4; ++fn)
                    acc[fm][fn] = __builtin_amdgcn_mfma_f32_16x16x32_bf16(a[fm], b[fn], acc[fm][fn], 0, 0, 0);
        }
        __syncthreads();
    }
    #pragma unroll
    for (int fm = 0; fm < 4; ++fm)
        #pragma unroll
        for (int j = 0; j < 4; ++j) {
            int m = wm + fm * 16 + l4 * 4 + j;
            #pragma unroll
            for (int fn = 0; fn < 4; ++fn) {
                int gn = nbase + wn + fn * 16 + l15;
                float v = acc[fm][fn][j];
                if (gn < 512) Abuf0[(size_t)m * 1024 + 512 + gn] = f2bf(tanhf(v + b_h[gn]));
                else          cbuf[(size_t)m * 512 + gn - 512] = tanhf(v + b_c[gn - 512]);
            }
        }
}

// ---------- fallback per-step GEMM (verified r9). grid (512) ----------
__global__ __launch_bounds__(256) void k_gemm32(
    const unsigned short* __restrict__ Abuf, const unsigned short* __restrict__ wordb,
    const unsigned short* __restrict__ WcatT, float* __restrict__ zpart, int t) {
    __shared__ short As[64 * 64];
    __shared__ short Bs[32 * 64];
    int tid = threadIdx.x;
    int bid = blockIdx.x;
    int ksb = bid >> 7, rem = bid & 127;
    int rowbase = (rem >> 6) * 64, nbase = (rem & 63) * 32;
    int wave = tid >> 6, lane = tid & 63;
    int wm = (wave & 1) * 32, wn = (wave >> 1) * 16;
    int l15 = lane & 15, l4 = lane >> 4;

    f32x4 acc[2];
    acc[0] = (f32x4){0.f, 0.f, 0.f, 0.f};
    acc[1] = (f32x4){0.f, 0.f, 0.f, 0.f};

    for (int it = 0; it < KCHUNK / 64; ++it) {
        int kbase = ksb * KCHUNK + it * 64;
        #pragma unroll
        for (int p = 0; p < 2; ++p) {
            int idx = p * 256 + tid;
            int row = idx >> 3, q = idx & 7;
            int k = kbase + q * 8;
            int gr = rowbase + row;
            float4 v;
            if (k < 1024) v = *(const float4*)(Abuf + (size_t)gr * 1024 + k);
            else          v = *(const float4*)(wordb + ((size_t)gr * T + t) * D + (k - 1024));
            *(float4*)&As[row * 64 + ((q ^ (row & 7)) << 3)] = v;
        }
        {
            int row = tid >> 3, q = tid & 7;
            float4 w = *(const float4*)(WcatT + (size_t)(nbase + row) * KCAT + kbase + q * 8);
            *(float4*)&Bs[row * 64 + ((q ^ (row & 7)) << 3)] = w;
        }
        __syncthreads();
        #pragma unroll
        for (int ks2 = 0; ks2 < 2; ++ks2) {
            int q = ks2 * 4 + l4;
            bf16x8 a[2], bb;
            #pragma unroll
            for (int fm = 0; fm < 2; ++fm) {
                int ar = wm + fm * 16 + l15;
                a[fm] = *(const bf16x8*)&As[ar * 64 + ((q ^ (ar & 7)) << 3)];
            }
            {
                int br = wn + l15;
                bb = *(const bf16x8*)&Bs[br * 64 + ((q ^ (br & 7)) << 3)];
            }
            #pragma unroll
            for (int fm = 0; fm < 2; ++fm)
                acc[fm] = __builtin_amdgcn_mfma_f32_16x16x32_bf16(a[fm], bb, acc[fm], 0, 0, 0);
        }
        __syncthreads();
    }
    float* zp = zpart + (size_t)ksb * B * H4;
    #pragma unroll
    for (int fm = 0; fm < 2; ++fm)
        #pragma unroll
        for (int j = 0; j < 4; ++j) {
            int m = rowbase + wm + fm * 16 + l4 * 4 + j;
            zp[(size_t)m * H4 + nbase + wn + l15] = acc[fm][j];
        }
}

// ---------- fallback / t=0 cell+attn (verified r9). grid (B, 4) ----------
__global__ __launch_bounds__(256) void k_step4(
    const float* __restrict__ zpart, const float* __restrict__ bias,
    const float* __restrict__ cb_cur, float* __restrict__ cb_nxt,
    unsigned short* __restrict__ Abuf,
    const unsigned short* __restrict__ Xb, const float* __restrict__ fscore,
    const float* __restrict__ w_a_h,
    float* __restrict__ out_h, float* __restrict__ out_m, float* __restrict__ out_a,
    int t_next) {
    __shared__ float red[12];
    __shared__ float sal[200];
    __shared__ float sp2[4][64][2];
    int b = blockIdx.x, quarter = blockIdx.y, tid = threadIdx.x;
    int lane = tid & 63, wid = tid >> 6;
    int n0 = tid * 2;
    float hp;
    if (t_next > 0) {
        float2 z[4];
        #pragma unroll
        for (int g = 0; g < 4; ++g) z[g] = *(const float2*)(bias + g * H + n0);
        #pragma unroll
        for (int ks = 0; ks < KS; ++ks) {
            const float* zp = zpart + ((size_t)ks * B + b) * H4;
            #pragma unroll
            for (int g = 0; g < 4; ++g) {
                float2 v = *(const float2*)(zp + g * H + n0);
                z[g].x += v.x; z[g].y += v.y;
            }
        }
        float2 cv = *(const float2*)(cb_cur + (size_t)b * H + n0);
        float cnx = sigf(z[1].x) * cv.x + sigf(z[0].x) * tanhf(z[2].x);
        float cny = sigf(z[1].y) * cv.y + sigf(z[0].y) * tanhf(z[2].y);
        float hnx = sigf(z[3].x) * tanhf(cnx);
        float hny = sigf(z[3].y) * tanhf(cny);
        if (quarter == 0) {
            int tp = t_next - 1;
            *(float2*)(cb_nxt + (size_t)b * H + n0) = make_float2(cnx, cny);
            *(float2*)(out_m + ((size_t)tp * B + b) * H + n0) = make_float2(cnx, cny);
            *(float2*)(out_h + ((size_t)b * T + tp) * H + n0) = make_float2(hnx, hny);
            ushort2 hu; hu.x = f2bf(hnx); hu.y = f2bf(hny);
            *(ushort2*)(Abuf + (size_t)b * 1024 + 512 + n0) = hu;
        }
        hp = hnx * w_a_h[n0] + hny * w_a_h[n0 + 1];
    } else {
        ushort2 hu = *(const ushort2*)(Abuf + (size_t)b * 1024 + 512 + n0);
        hp = bf2f(hu.x) * w_a_h[n0] + bf2f(hu.y) * w_a_h[n0 + 1];
    }
    if (t_next >= T) return;

    float s = wred_sum(hp);
    if (lane == 0) red[wid] = s;
    __syncthreads();
    float hs = red[0] + red[1] + red[2] + red[3];
    float scv = (tid < L) ? tanhf(hs + fscore[b * L + tid]) : -3.0e38f;
    float m = wred_max(scv);
    if (lane == 0) red[4 + wid] = m;
    __syncthreads();
    float mx = fmaxf(fmaxf(red[4], red[5]), fmaxf(red[6], red[7]));
    float ex = (tid < L) ? expf(scv - mx) : 0.f;
    float es = wred_sum(ex);
    if (lane == 0) red[8 + wid] = es;
    __syncthreads();
    float denom = red[8] + red[9] + red[10] + red[11];
    float al = ex / denom;
    if (tid < L) {
        sal[tid] = al;
        if (quarter == 0) out_a[((size_t)b * T + t_next) * L + tid] = al;
    }
    __syncthreads();

    int fi = tid & 63, lg = tid >> 6;
    const unsigned* xb32 = (const unsigned*)(Xb + (size_t)b * L * F2) + quarter * 64 + fi;
    int l0 = lg * 49;
    float a0 = 0.f, a1 = 0.f;
    for (int sblk = 0; sblk < 49; sblk += 7) {
        unsigned u[7];
        #pragma unroll
        for (int j = 0; j < 7; ++j) u[j] = xb32[(size_t)(l0 + sblk + j) * 256];
        #pragma unroll
        for (int j = 0; j < 7; ++j) {
            float w = sal[l0 + sblk + j];
            a0 += bf2f((unsigned short)(u[j] & 0xFFFF)) * w;
            a1 += bf2f((unsigned short)(u[j] >> 16)) * w;
        }
    }
    sp2[lg][fi][0] = a0; sp2[lg][fi][1] = a1;
    __syncthreads();
    if (tid < 64) {
        ushort2 cu;
        cu.x = f2bf(sp2[0][tid][0] + sp2[1][tid][0] + sp2[2][tid][0] + sp2[3][tid][0]);
        cu.y = f2bf(sp2[0][tid][1] + sp2[1][tid][1] + sp2[2][tid][1] + sp2[3][tid][1]);
        *(ushort2*)(Abuf + (size_t)b * 1024 + (quarter * 64 + tid) * 2) = cu;
    }
}

// ---------- fused per-step kernel: gemm + cell (last-block) + attn (flag-synced) ----------
// grid 1024: bid<512 gemm role (verified k_gemm32 body), bid>=512 attn role.
// cnts: [0..31] cell-tile counters (rowtile*16 + j), [32..33] h-ready counters.
// All counters monotonic; target at step t is 16*(t+1); zeroed by k_mred each launch.
__global__ __launch_bounds__(256, 4) void k_fused(
    const unsigned short* __restrict__ Abuf, const unsigned short* __restrict__ wordb,
    const unsigned short* __restrict__ WcatT, float* __restrict__ zpart,
    const float* __restrict__ bias, const float* __restrict__ cb_cur,
    float* __restrict__ cb_nxt, unsigned short* __restrict__ Abuf_w,
    const unsigned short* __restrict__ Xb, const float* __restrict__ fscore,
    const float* __restrict__ w_a_h,
    float* __restrict__ out_h, float* __restrict__ out_m, float* __restrict__ out_a,
    unsigned* __restrict__ cnts, int t) {
    __shared__ short As[64 * 64];
    __shared__ short Bs[32 * 64];
    __shared__ float red[12];
    __shared__ float sal[200];
    __shared__ float sp2[4][64][2];
    __shared__ unsigned sIsLast;
    int tid = threadIdx.x;
    int bid = blockIdx.x;
    unsigned target = 16u * (unsigned)(t + 1);

    if (bid < 512) {
        // ---- gemm role (body identical to verified k_gemm32) ----
        int ksb = bid >> 7, rem = bid & 127;
        int rowbase = (rem >> 6) * 64, nbase = (rem & 63) * 32;
        int wave = tid >> 6, lane = tid & 63;
        int wm = (wave & 1) * 32, wn = (wave >> 1) * 16;
        int l15 = lane & 15, l4 = lane >> 4;

        f32x4 acc[2];
        acc[0] = (f32x4){0.f, 0.f, 0.f, 0.f};
        acc[1] = (f32x4){0.f, 0.f, 0.f, 0.f};

        for (int it = 0; it < KCHUNK / 64; ++it) {
            int kbase = ksb * KCHUNK + it * 64;
            #pragma unroll
            for (int p = 0; p < 2; ++p) {
                int idx = p * 256 + tid;
                int row = idx >> 3, q = idx & 7;
                int k = kbase + q * 8;
                int gr = rowbase + row;
                float4 v;
                if (k < 1024) v = *(const float4*)(Abuf + (size_t)gr * 1024 + k);
                else          v = *(const float4*)(wordb + ((size_t)gr * T + t) * D + (k - 1024));
                *(float4*)&As[row * 64 + ((q ^ (row & 7)) << 3)] = v;
            }
            {
                int row = tid >> 3, q = tid & 7;
                float4 w = *(const float4*)(WcatT + (size_t)(nbase + row) * KCAT + kbase + q * 8);
                *(float4*)&Bs[row * 64 + ((q ^ (row & 7)) << 3)] = w;
            }
            __syncthreads();
            #pragma unroll
            for (int ks2 = 0; ks2 < 2; ++ks2) {
                int q = ks2 * 4 + l4;
                bf16x8 a[2], bb;
                #pragma unroll
                for (int fm = 0; fm < 2; ++fm) {
                    int ar = wm + fm * 16 + l15;
                    a[fm] = *(const bf16x8*)&As[ar * 64 + ((q ^ (ar & 7)) << 3)];
                }
                {
                    int br = wn + l15;
                    bb = *(const bf16x8*)&Bs[br * 64 + ((q ^ (br & 7)) << 3)];
                }
                #pragma unroll
                for (int fm = 0; fm < 2; ++fm)
                    acc[fm] = __builtin_amdgcn_mfma_f32_16x16x32_bf16(a[fm], bb, acc[fm], 0, 0, 0);
            }
            __syncthreads();
        }
        float* zp = zpart + (size_t)ksb * B * H4;
        #pragma unroll
        for (int fm = 0; fm < 2; ++fm)
            #pragma unroll
            for (int j = 0; j < 4; ++j) {
                int m = rowbase + wm + fm * 16 + l4 * 4 + j;
                zp[(size_t)m * H4 + nbase + wn + l15] = acc[fm][j];
            }

        // ---- signal tile done; 16th finisher computes the cell for (rowtile, j) ----
        int rowtile = rem >> 6;
        int ccIdx = rowtile * 16 + ((nbase & 511) >> 5);
        __threadfence();
        __syncthreads();
        if (tid == 0) {
            unsigned old = atomicAdd(&cnts[ccIdx], 1u);
            sIsLast = (old == target - 1u) ? 1u : 0u;
        }
        __syncthreads();
        if (sIsLast) {
            __threadfence();   // acquire: other 15 blocks' zpart tiles
            int ncb = nbase & 511;
            for (int i = tid; i < 64 * 32; i += 256) {
                int r = i >> 5, nn = i & 31;
                int b = rowbase + r, n = ncb + nn;
                float z0 = bias[n], z1 = bias[512 + n], z2 = bias[1024 + n], z3 = bias[1536 + n];
                #pragma unroll
                for (int ks = 0; ks < KS; ++ks) {
                    const float* zq = zpart + ((size_t)ks * B + b) * H4;
                    z0 += zq[n]; z1 += zq[512 + n]; z2 += zq[1024 + n]; z3 += zq[1536 + n];
                }
                float cv = cb_cur[(size_t)b * H + n];
                float cn = sigf(z1) * cv + sigf(z0) * tanhf(z2);
                float hn = sigf(z3) * tanhf(cn);
                cb_nxt[(size_t)b * H + n] = cn;
                out_m[((size_t)t * B + b) * H + n] = cn;
                out_h[((size_t)b * T + t) * H + n] = hn;
                Abuf_w[(size_t)b * 1024 + 512 + n] = f2bf(hn);
            }
            __threadfence();   // release h
            __syncthreads();
            if (tid == 0) atomicAdd(&cnts[32 + rowtile], 1u);
        }
        return;
    }

    // ---- attn role: (b, quarter) waits for its rowtile's h, then verified attn body ----
    int t_next = t + 1;
    if (t_next >= T) return;
    int bid2 = bid - 512;
    int b = bid2 >> 2, quarter = bid2 & 3;
    int rowtile = b >> 6;
    if (tid == 0) {
        while (__hip_atomic_load(&cnts[32 + rowtile], __ATOMIC_RELAXED,
                                 __HIP_MEMORY_SCOPE_AGENT) < target)
            __builtin_amdgcn_s_sleep(2);
    }
    __syncthreads();
    __threadfence();   // acquire: h written by cell finishers

    int lane = tid & 63, wid = tid >> 6;
    int n0 = tid * 2;
    ushort2 hu = *(const ushort2*)(Abuf_w + (size_t)b * 1024 + 512 + n0);
    float hp = bf2f(hu.x) * w_a_h[n0] + bf2f(hu.y) * w_a_h[n0 + 1];

    float s = wred_sum(hp);
    if (lane == 0) red[wid] = s;
    __syncthreads();
    float hs = red[0] + red[1] + red[2] + red[3];
    float scv = (tid < L) ? tanhf(hs + fscore[b * L + tid]) : -3.0e38f;
    float m = wred_max(scv);
    if (lane == 0) red[4 + wid] = m;
    __syncthreads();
    float mx = fmaxf(fmaxf(red[4], red[5]), fmaxf(red[6], red[7]));
    float ex = (tid < L) ? expf(scv - mx) : 0.f;
    float es = wred_sum(ex);
    if (lane == 0) red[8 + wid] = es;
    __syncthreads();
    float denom = red[8] + red[9] + red[10] + red[11];
    float al = ex / denom;
    if (tid < L) {
        sal[tid] = al;
        if (quarter == 0) out_a[((size_t)b * T + t_next) * L + tid] = al;
    }
    __syncthreads();

    int fi = tid & 63, lg = tid >> 6;
    const unsigned* xb32 = (const unsigned*)(Xb + (size_t)b * L * F2) + quarter * 64 + fi;
    int l0 = lg * 49;
    float a0 = 0.f, a1 = 0.f;
    for (int sblk = 0; sblk < 49; sblk += 7) {
        unsigned u[7];
        #pragma unroll
        for (int j = 0; j < 7; ++j) u[j] = xb32[(size_t)(l0 + sblk + j) * 256];
        #pragma unroll
        for (int j = 0; j < 7; ++j) {
            float w = sal[l0 + sblk + j];
            a0 += bf2f((unsigned short)(u[j] & 0xFFFF)) * w;
            a1 += bf2f((unsigned short)(u[j] >> 16)) * w;
        }
    }
    sp2[lg][fi][0] = a0; sp2[lg][fi][1] = a1;
    __syncthreads();
    if (tid < 64) {
        ushort2 cu;
        cu.x = f2bf(sp2[0][tid][0] + sp2[1][tid][0] + sp2[2][tid][0] + sp2[3][tid][0]);
        cu.y = f2bf(sp2[0][tid][1] + sp2[1][tid][1] + sp2[2][tid][1] + sp2[3][tid][1]);
        *(ushort2*)(Abuf_w + (size_t)b * 1024 + (quarter * 64 + tid) * 2) = cu;
    }
}

extern "C" void kernel_launch(void* const* d_in, const int* in_sizes, int n_in,
                              void* d_out, int out_size, void* d_ws, size_t ws_size,
                              hipStream_t stream) {
    (void)in_sizes; (void)n_in; (void)out_size; (void)ws_size;
    const float* X     = (const float*)d_in[0];
    const float* word  = (const float*)d_in[1];
    const float* w_h   = (const float*)d_in[2];
    const float* b_h   = (const float*)d_in[3];
    const float* w_c   = (const float*)d_in[4];
    const float* b_c   = (const float*)d_in[5];
    const float* w_a_h = (const float*)d_in[6];
    const float* w_a   = (const float*)d_in[7];
    const float* b_a   = (const float*)d_in[8];
    const float* k_w   = (const float*)d_in[9];
    const float* r_w   = (const float*)d_in[10];
    const float* bias  = (const float*)d_in[11];

    float* out_h = (float*)d_out;
    float* out_m = out_h + (size_t)B * T * H;
    float* out_a = out_m + (size_t)T * B * H;

    char* p = (char*)d_ws;
    unsigned short* Xb    = (unsigned short*)p; p += (size_t)B * L * F2 * 2;
    unsigned short* WcatT = (unsigned short*)p; p += (size_t)H4 * KCAT * 2;
    unsigned short* wiT   = (unsigned short*)p; p += (size_t)1024 * 512 * 2;
    unsigned short* wordb = (unsigned short*)p; p += (size_t)B * T * D * 2;
    unsigned short* fmb   = (unsigned short*)p; p += (size_t)B * F2 * 2;
    unsigned short* Abuf  = (unsigned short*)p; p += (size_t)B * 1024 * 2;
    float* fscore = (float*)p; p += (size_t)B * L * 4;
    float* cb0    = (float*)p; p += (size_t)B * H * 4;
    float* cb1    = (float*)p; p += (size_t)B * H * 4;
    float* zpart  = (float*)p; p += (size_t)KS * B * H4 * 4;
    unsigned* cnts = (unsigned*)p; p += 64 * 4;
    // fmpart (B*7*512 fp32 = 1.84 MB) aliases zpart (4.19 MB); lifetimes disjoint
    float* fmpart = zpart;

    k_prep2<<<dim3(B, 7), 256, 0, stream>>>(X, w_a, b_a, Xb, fscore, fmpart);
    k_mred<<<B, 256, 0, stream>>>(fmpart, fmb, cnts);
    k_castw<<<512, 256, 0, stream>>>(word, wordb);
    k_trW<<<dim3(16, 32, 3), 256, 0, stream>>>(k_w, r_w, WcatT);
    k_trI<<<dim3(16, 8, 2), 256, 0, stream>>>(w_h, w_c, wiT);
    k_init_gemm<<<8, 256, 0, stream>>>(fmb, wiT, b_h, b_c, Abuf, cb0);

    // attn(0) from h0
    k_step4<<<dim3(B, 4), 256, 0, stream>>>(zpart, bias, cb0, cb1, Abuf, Xb,
                                            fscore, w_a_h, out_h, out_m, out_a, 0);

    float* cb[2] = {cb0, cb1};
    int dev = 0;
    hipGetDevice(&dev);
    int coopOK = 0;
    hipDeviceGetAttribute(&coopOK, hipDeviceAttributeCooperativeLaunch, dev);
    bool coop = (coopOK != 0);
    for (int t = 0; t < T && coop; ++t) {
        const unsigned short* AbufC = Abuf;
        const float* cbc = cb[t & 1];
        float* cbn = cb[(t + 1) & 1];
        void* args[] = {(void*)&AbufC, (void*)&wordb, (void*)&WcatT, (void*)&zpart,
                        (void*)&bias, (void*)&cbc, (void*)&cbn, (void*)&Abuf,
                        (void*)&Xb, (void*)&fscore, (void*)&w_a_h,
                        (void*)&out_h, (void*)&out_m, (void*)&out_a,
                        (void*)&cnts, (void*)&t};
        hipError_t e = hipLaunchCooperativeKernel((void*)k_fused, dim3(1024), dim3(256),
                                                  args, 0, stream);
        if (e != hipSuccess) { coop = false; break; }
    }
    if (!coop) {
        // fallback: verified r9 sequence (attn(0) already done above)
        for (int t = 0; t < T; ++t) {
            k_gemm32<<<512, 256, 0, stream>>>(Abuf, wordb, WcatT, zpart, t);
            k_step4<<<dim3(B, 4), 256, 0, stream>>>(zpart, bias, cb[t & 1], cb[(t + 1) & 1],
                                                    Abuf, Xb, fscore, w_a_h,
                                                    out_h, out_m, out_a, t + 1);
        }
    }
}

// Round 11
// 555.679 us; speedup vs baseline: 6.9012x; 6.9012x over previous
//
#include <hip/hip_runtime.h>
#include <math.h>

#define B  128
#define L  196
#define F2 512
#define T  32
#define D  256
#define H  512
#define H4 2048
#define KCAT 1280
#define KS 4
#define KCHUNK 320   // KCAT/KS

typedef __attribute__((ext_vector_type(8))) short bf16x8;
typedef __attribute__((ext_vector_type(4))) float f32x4;

__device__ __forceinline__ float sigf(float x) { return 1.0f / (1.0f + expf(-x)); }
__device__ __forceinline__ unsigned short f2bf(float x) {
    unsigned u = __float_as_uint(x);
    u += 0x7FFF + ((u >> 16) & 1);
    return (unsigned short)(u >> 16);
}
__device__ __forceinline__ float bf2f(unsigned short s) {
    return __uint_as_float(((unsigned)s) << 16);
}
__device__ __forceinline__ float wred_sum(float v) {
    for (int o = 32; o > 0; o >>= 1) v += __shfl_down(v, o);
    return v;
}

// ---------- setup (all verified round 5/7/9) ----------

__global__ void k_prep2(const float* __restrict__ X, const float* __restrict__ w_a,
                        const float* __restrict__ b_a, unsigned short* __restrict__ Xb,
                        float* __restrict__ fscore, float* __restrict__ fmpart) {
    __shared__ float sp[8][512];
    int b = blockIdx.x, g = blockIdx.y, tid = threadIdx.x;
    int rowi = tid >> 5, lane32 = tid & 31;
    int f0 = tid * 2;
    float2 acc = make_float2(0.f, 0.f);
    for (int s = 0; s < 4; ++s) {
        int li = s * 8 + rowi;
        float4 part[4];
        if (li < 28) {
            size_t row = (size_t)b * L + g * 28 + li;
            const float* src = X + row * F2;
            unsigned short* dst = Xb + row * F2;
            float sc = 0.f;
            #pragma unroll
            for (int j = 0; j < 4; ++j) {
                int f = j * 128 + lane32 * 4;
                float4 v = *(const float4*)(src + f);
                float4 w = *(const float4*)(w_a + f);
                sc += v.x * w.x + v.y * w.y + v.z * w.z + v.w * w.w;
                part[j] = v;
                ushort4 u;
                u.x = f2bf(v.x); u.y = f2bf(v.y); u.z = f2bf(v.z); u.w = f2bf(v.w);
                *(ushort4*)(dst + f) = u;
            }
            for (int o = 16; o > 0; o >>= 1) sc += __shfl_down(sc, o, 32);
            if (lane32 == 0) fscore[row] = sc + b_a[0];
        } else {
            #pragma unroll
            for (int j = 0; j < 4; ++j) part[j] = make_float4(0.f, 0.f, 0.f, 0.f);
        }
        __syncthreads();
        #pragma unroll
        for (int j = 0; j < 4; ++j)
            *(float4*)&sp[rowi][j * 128 + lane32 * 4] = part[j];
        __syncthreads();
        #pragma unroll
        for (int r = 0; r < 8; ++r) { acc.x += sp[r][f0]; acc.y += sp[r][f0 + 1]; }
    }
    *(float2*)&fmpart[((size_t)b * 7 + g) * 512 + f0] = acc;
}

__global__ void k_mred(const float* __restrict__ fmpart, unsigned short* __restrict__ fmb) {
    int b = blockIdx.x, tid = threadIdx.x;
    int f0 = tid * 2;
    float2 acc = make_float2(0.f, 0.f);
    #pragma unroll
    for (int g = 0; g < 7; ++g) {
        float2 v = *(const float2*)&fmpart[((size_t)b * 7 + g) * 512 + f0];
        acc.x += v.x; acc.y += v.y;
    }
    ushort2 u; u.x = f2bf(acc.x * (1.0f / L)); u.y = f2bf(acc.y * (1.0f / L));
    *(ushort2*)(fmb + (size_t)b * F2 + f0) = u;
}

__global__ void k_castw(const float* __restrict__ src, unsigned short* __restrict__ dst) {
    size_t i = ((size_t)blockIdx.x * 256 + threadIdx.x) * 8;
    float4 v0 = *(const float4*)(src + i);
    float4 v1 = *(const float4*)(src + i + 4);
    ushort4 u0, u1;
    u0.x = f2bf(v0.x); u0.y = f2bf(v0.y); u0.z = f2bf(v0.z); u0.w = f2bf(v0.w);
    u1.x = f2bf(v1.x); u1.y = f2bf(v1.y); u1.z = f2bf(v1.z); u1.w = f2bf(v1.w);
    *(ushort4*)(dst + i) = u0;
    *(ushort4*)(dst + i + 4) = u1;
}

__global__ void k_trW(const float* __restrict__ k_w, const float* __restrict__ r_w,
                      unsigned short* __restrict__ WcatT) {
    int job = blockIdx.z;
    if (job == 2 && blockIdx.x >= 8) return;
    const float* src; int colOff;
    if (job == 0)      { src = k_w + (size_t)256 * H4; colOff = 0; }
    else if (job == 1) { src = r_w;                    colOff = 512; }
    else               { src = k_w;                    colOff = 1024; }
    __shared__ float Ls[32][65];
    int r0 = blockIdx.x * 32, c0 = blockIdx.y * 64;
    int tid = threadIdx.x;
    int r = tid >> 3, c8 = (tid & 7) * 8;
    const float* s = src + (size_t)(r0 + r) * H4 + c0 + c8;
    #pragma unroll
    for (int j = 0; j < 8; ++j) Ls[r][c8 + j] = s[j];
    __syncthreads();
    int cc = tid >> 2, q = tid & 3;
    unsigned short tmp[8];
    #pragma unroll
    for (int j = 0; j < 8; ++j) tmp[j] = f2bf(Ls[q * 8 + j][cc]);
    *(float4*)(WcatT + (size_t)(c0 + cc) * KCAT + colOff + r0 + q * 8) = *(float4*)tmp;
}

__global__ void k_trI(const float* __restrict__ w_h, const float* __restrict__ w_c,
                      unsigned short* __restrict__ wiT) {
    int job = blockIdx.z;
    const float* src = job ? w_c : w_h;
    unsigned short* dst = wiT + (size_t)job * 512 * 512;
    __shared__ float Ls[32][65];
    int r0 = blockIdx.x * 32, c0 = blockIdx.y * 64;
    int tid = threadIdx.x;
    int r = tid >> 3, c8 = (tid & 7) * 8;
    const float* s = src + (size_t)(r0 + r) * 512 + c0 + c8;
    #pragma unroll
    for (int j = 0; j < 8; ++j) Ls[r][c8 + j] = s[j];
    __syncthreads();
    int cc = tid >> 2, q = tid & 3;
    unsigned short tmp[8];
    #pragma unroll
    for (int j = 0; j < 8; ++j) tmp[j] = f2bf(Ls[q * 8 + j][cc]);
    *(float4*)(dst + (size_t)(c0 + cc) * 512 + r0 + q * 8) = *(float4*)tmp;
}

// ---------- init-state GEMM (MFMA, verified) ----------
__global__ __launch_bounds__(256) void k_init_gemm(
    const unsigned short* __restrict__ A, const unsigned short* __restrict__ Bt,
    const float* __restrict__ b_h, const float* __restrict__ b_c,
    unsigned short* __restrict__ Abuf0, float* __restrict__ cbuf) {
    __shared__ short As[128 * 64];
    __shared__ short Bs[128 * 64];
    int tid = threadIdx.x;
    int nbase = blockIdx.x * 128;
    int wave = tid >> 6, lane = tid & 63;
    int wm = (wave >> 1) * 64, wn = (wave & 1) * 64;
    int l15 = lane & 15, l4 = lane >> 4;

    f32x4 acc[4][4];
    #pragma unroll
    for (int i = 0; i < 4; ++i)
        #pragma unroll
        for (int j = 0; j < 4; ++j) acc[i][j] = (f32x4){0.f, 0.f, 0.f, 0.f};

    for (int it = 0; it < 8; ++it) {
        int kbase = it * 64;
        #pragma unroll
        for (int ch = 0; ch < 4; ++ch) {
            int idx = ch * 256 + tid;
            int row = idx >> 3, q = idx & 7;
            int k = kbase + q * 8;
            float4 v = *(const float4*)(A + (size_t)row * 512 + k);
            *(float4*)&As[row * 64 + ((q ^ (row & 7)) << 3)] = v;
            float4 w = *(const float4*)(Bt + (size_t)(nbase + row) * 512 + k);
            *(float4*)&Bs[row * 64 + ((q ^ (row & 7)) << 3)] = w;
        }
        __syncthreads();
        #pragma unroll
        for (int ks = 0; ks < 2; ++ks) {
            bf16x8 a[4], b[4];
            #pragma unroll
            for (int f = 0; f < 4; ++f) {
                int ar = wm + f * 16 + l15;
                int q = ks * 4 + l4;
                a[f] = *(const bf16x8*)&As[ar * 64 + ((q ^ (ar & 7)) << 3)];
                int br = wn + f * 16 + l15;
                b[f] = *(const bf16x8*)&Bs[br * 64 + ((q ^ (br & 7)) << 3)];
            }
            #pragma unroll
            for (int fm = 0; fm < 4; ++fm)
                #pragma unroll
                for (int fn = 0; fn < 4; ++fn)
                    acc[fm][fn] = __builtin_amdgcn_mfma_f32_16x16x32_bf16(a[fm], b[fn], acc[fm][fn], 0, 0, 0);
        }
        __syncthreads();
    }
    #pragma unroll
    for (int fm = 0; fm < 4; ++fm)
        #pragma unroll
        for (int j = 0; j < 4; ++j) {
            int m = wm + fm * 16 + l4 * 4 + j;
            #pragma unroll
            for (int fn = 0; fn < 4; ++fn) {
                int gn = nbase + wn + fn * 16 + l15;
                float v = acc[fm][fn][j];
                if (gn < 512) Abuf0[(size_t)m * 1024 + 512 + gn] = f2bf(tanhf(v + b_h[gn]));
                else          cbuf[(size_t)m * 512 + gn - 512] = tanhf(v + b_c[gn - 512]);
            }
        }
}

// ---------- per-step gates GEMM: 64x32 tiles, 512 blocks, LDS double-buffered ----------
// One barrier per K-iter: loads for it+1 issue before MFMA(it); vmcnt wait lands at the
// LDS-store after the MFMA. Buffer written at iter it was last read at it-1, whose reads
// completed before the top-of-it barrier -> race-free with a single barrier.
__global__ __launch_bounds__(256) void k_gemm32(
    const unsigned short* __restrict__ Abuf, const unsigned short* __restrict__ wordb,
    const unsigned short* __restrict__ WcatT, float* __restrict__ zpart, int t) {
    __shared__ short As[2][64 * 64];
    __shared__ short Bs[2][32 * 64];
    int tid = threadIdx.x;
    int bid = blockIdx.x;
    int ksb = bid >> 7, rem = bid & 127;
    int rowbase = (rem >> 6) * 64, nbase = (rem & 63) * 32;
    int wave = tid >> 6, lane = tid & 63;
    int wm = (wave & 1) * 32, wn = (wave >> 1) * 16;
    int l15 = lane & 15, l4 = lane >> 4;

    // staging indices
    int arow = tid >> 3, aq = tid & 7;          // A: 2 rows/thread via p loop
    int brow = tid >> 3, bq = tid & 7;          // B: 1 float4/thread

    f32x4 acc[2];
    acc[0] = (f32x4){0.f, 0.f, 0.f, 0.f};
    acc[1] = (f32x4){0.f, 0.f, 0.f, 0.f};

    float4 va[2], wb;
    // preload iter 0
    {
        int kbase = ksb * KCHUNK;
        #pragma unroll
        for (int p = 0; p < 2; ++p) {
            int row = (p * 256 + tid) >> 3;
            int k = kbase + aq * 8;
            int gr = rowbase + row;
            if (k < 1024) va[p] = *(const float4*)(Abuf + (size_t)gr * 1024 + k);
            else          va[p] = *(const float4*)(wordb + ((size_t)gr * T + t) * D + (k - 1024));
        }
        wb = *(const float4*)(WcatT + (size_t)(nbase + brow) * KCAT + kbase + bq * 8);
    }
    // store buf 0
    #pragma unroll
    for (int p = 0; p < 2; ++p) {
        int row = (p * 256 + tid) >> 3;
        *(float4*)&As[0][row * 64 + ((aq ^ (row & 7)) << 3)] = va[p];
    }
    *(float4*)&Bs[0][brow * 64 + ((bq ^ (brow & 7)) << 3)] = wb;

    int cur = 0;
    for (int it = 0; it < KCHUNK / 64; ++it) {
        __syncthreads();   // buf[cur] ready for all
        if (it < KCHUNK / 64 - 1) {
            int kbase = ksb * KCHUNK + (it + 1) * 64;
            #pragma unroll
            for (int p = 0; p < 2; ++p) {
                int row = (p * 256 + tid) >> 3;
                int k = kbase + aq * 8;
                int gr = rowbase + row;
                if (k < 1024) va[p] = *(const float4*)(Abuf + (size_t)gr * 1024 + k);
                else          va[p] = *(const float4*)(wordb + ((size_t)gr * T + t) * D + (k - 1024));
            }
            wb = *(const float4*)(WcatT + (size_t)(nbase + brow) * KCAT + kbase + bq * 8);
        }
        #pragma unroll
        for (int ks2 = 0; ks2 < 2; ++ks2) {
            int q = ks2 * 4 + l4;
            bf16x8 a[2], bb;
            #pragma unroll
            for (int fm = 0; fm < 2; ++fm) {
                int ar = wm + fm * 16 + l15;
                a[fm] = *(const bf16x8*)&As[cur][ar * 64 + ((q ^ (ar & 7)) << 3)];
            }
            {
                int br = wn + l15;
                bb = *(const bf16x8*)&Bs[cur][br * 64 + ((q ^ (br & 7)) << 3)];
            }
            #pragma unroll
            for (int fm = 0; fm < 2; ++fm)
                acc[fm] = __builtin_amdgcn_mfma_f32_16x16x32_bf16(a[fm], bb, acc[fm], 0, 0, 0);
        }
        if (it < KCHUNK / 64 - 1) {
            #pragma unroll
            for (int p = 0; p < 2; ++p) {
                int row = (p * 256 + tid) >> 3;
                *(float4*)&As[cur ^ 1][row * 64 + ((aq ^ (row & 7)) << 3)] = va[p];
            }
            *(float4*)&Bs[cur ^ 1][brow * 64 + ((bq ^ (brow & 7)) << 3)] = wb;
            cur ^= 1;
        }
    }
    float* zp = zpart + (size_t)ksb * B * H4;
    #pragma unroll
    for (int fm = 0; fm < 2; ++fm)
        #pragma unroll
        for (int j = 0; j < 4; ++j) {
            int m = rowbase + wm + fm * 16 + l4 * 4 + j;
            zp[(size_t)m * H4 + nbase + wn + l15] = acc[fm][j];
        }
}

// ---------- fused cell + attention. grid (B, 4), 256 thr ----------
// Softmax without max-subtraction: score = tanh(.) in [-1,1], exp in [0.37,2.72]
// (shift-invariant, mathematically identical) -> one fewer reduce+barrier phase.
__global__ __launch_bounds__(256) void k_step4(
    const float* __restrict__ zpart, const float* __restrict__ bias,
    const float* __restrict__ cb_cur, float* __restrict__ cb_nxt,
    unsigned short* __restrict__ Abuf,
    const unsigned short* __restrict__ Xb, const float* __restrict__ fscore,
    const float* __restrict__ w_a_h,
    float* __restrict__ out_h, float* __restrict__ out_m, float* __restrict__ out_a,
    int t_next) {
    __shared__ float red[8];
    __shared__ float sal[200];
    __shared__ float sp2[4][64][2];
    int b = blockIdx.x, quarter = blockIdx.y, tid = threadIdx.x;
    int lane = tid & 63, wid = tid >> 6;
    int n0 = tid * 2;
    float hp;
    if (t_next > 0) {
        float2 z[4];
        #pragma unroll
        for (int g = 0; g < 4; ++g) z[g] = *(const float2*)(bias + g * H + n0);
        #pragma unroll
        for (int ks = 0; ks < KS; ++ks) {
            const float* zp = zpart + ((size_t)ks * B + b) * H4;
            #pragma unroll
            for (int g = 0; g < 4; ++g) {
                float2 v = *(const float2*)(zp + g * H + n0);
                z[g].x += v.x; z[g].y += v.y;
            }
        }
        float2 cv = *(const float2*)(cb_cur + (size_t)b * H + n0);
        float cnx = sigf(z[1].x) * cv.x + sigf(z[0].x) * tanhf(z[2].x);
        float cny = sigf(z[1].y) * cv.y + sigf(z[0].y) * tanhf(z[2].y);
        float hnx = sigf(z[3].x) * tanhf(cnx);
        float hny = sigf(z[3].y) * tanhf(cny);
        if (quarter == 0) {
            int tp = t_next - 1;
            *(float2*)(cb_nxt + (size_t)b * H + n0) = make_float2(cnx, cny);
            *(float2*)(out_m + ((size_t)tp * B + b) * H + n0) = make_float2(cnx, cny);
            *(float2*)(out_h + ((size_t)b * T + tp) * H + n0) = make_float2(hnx, hny);
            ushort2 hu; hu.x = f2bf(hnx); hu.y = f2bf(hny);
            *(ushort2*)(Abuf + (size_t)b * 1024 + 512 + n0) = hu;
        }
        hp = hnx * w_a_h[n0] + hny * w_a_h[n0 + 1];
    } else {
        ushort2 hu = *(const ushort2*)(Abuf + (size_t)b * 1024 + 512 + n0);
        hp = bf2f(hu.x) * w_a_h[n0] + bf2f(hu.y) * w_a_h[n0 + 1];
    }
    if (t_next >= T) return;

    float s = wred_sum(hp);
    if (lane == 0) red[wid] = s;
    __syncthreads();
    float hs = red[0] + red[1] + red[2] + red[3];
    float scv = (tid < L) ? tanhf(hs + fscore[b * L + tid]) : 0.f;
    float ex = (tid < L) ? expf(scv) : 0.f;   // bounded: scv in [-1,1]
    float es = wred_sum(ex);
    if (lane == 0) red[4 + wid] = es;
    __syncthreads();
    float denom = red[4] + red[5] + red[6] + red[7];
    float al = ex / denom;
    if (tid < L) {
        sal[tid] = al;
        if (quarter == 0) out_a[((size_t)b * T + t_next) * L + tid] = al;
    }
    __syncthreads();

    int fi = tid & 63, lg = tid >> 6;
    const unsigned* xb32 = (const unsigned*)(Xb + (size_t)b * L * F2) + quarter * 64 + fi;
    int l0 = lg * 49;
    float a0 = 0.f, a1 = 0.f;
    for (int sblk = 0; sblk < 49; sblk += 7) {
        unsigned u[7];
        #pragma unroll
        for (int j = 0; j < 7; ++j) u[j] = xb32[(size_t)(l0 + sblk + j) * 256];
        #pragma unroll
        for (int j = 0; j < 7; ++j) {
            float w = sal[l0 + sblk + j];
            a0 += bf2f((unsigned short)(u[j] & 0xFFFF)) * w;
            a1 += bf2f((unsigned short)(u[j] >> 16)) * w;
        }
    }
    sp2[lg][fi][0] = a0; sp2[lg][fi][1] = a1;
    __syncthreads();
    if (tid < 64) {
        ushort2 cu;
        cu.x = f2bf(sp2[0][tid][0] + sp2[1][tid][0] + sp2[2][tid][0] + sp2[3][tid][0]);
        cu.y = f2bf(sp2[0][tid][1] + sp2[1][tid][1] + sp2[2][tid][1] + sp2[3][tid][1]);
        *(ushort2*)(Abuf + (size_t)b * 1024 + (quarter * 64 + tid) * 2) = cu;
    }
}

extern "C" void kernel_launch(void* const* d_in, const int* in_sizes, int n_in,
                              void* d_out, int out_size, void* d_ws, size_t ws_size,
                              hipStream_t stream) {
    (void)in_sizes; (void)n_in; (void)out_size; (void)ws_size;
    const float* X     = (const float*)d_in[0];
    const float* word  = (const float*)d_in[1];
    const float* w_h   = (const float*)d_in[2];
    const float* b_h   = (const float*)d_in[3];
    const float* w_c   = (const float*)d_in[4];
    const float* b_c   = (const float*)d_in[5];
    const float* w_a_h = (const float*)d_in[6];
    const float* w_a   = (const float*)d_in[7];
    const float* b_a   = (const float*)d_in[8];
    const float* k_w   = (const float*)d_in[9];
    const float* r_w   = (const float*)d_in[10];
    const float* bias  = (const float*)d_in[11];

    float* out_h = (float*)d_out;
    float* out_m = out_h + (size_t)B * T * H;
    float* out_a = out_m + (size_t)T * B * H;

    // ws layout — total 39,290,880 bytes (proven footprint)
    char* p = (char*)d_ws;
    unsigned short* Xb    = (unsigned short*)p; p += (size_t)B * L * F2 * 2;
    unsigned short* WcatT = (unsigned short*)p; p += (size_t)H4 * KCAT * 2;
    unsigned short* wiT   = (unsigned short*)p; p += (size_t)1024 * 512 * 2;
    unsigned short* wordb = (unsigned short*)p; p += (size_t)B * T * D * 2;
    unsigned short* fmb   = (unsigned short*)p; p += (size_t)B * F2 * 2;
    unsigned short* Abuf  = (unsigned short*)p; p += (size_t)B * 1024 * 2;
    float* fscore = (float*)p; p += (size_t)B * L * 4;
    float* cb0    = (float*)p; p += (size_t)B * H * 4;
    float* cb1    = (float*)p; p += (size_t)B * H * 4;
    float* zpart  = (float*)p; p += (size_t)KS * B * H4 * 4;
    // fmpart (B*7*512 fp32 = 1.84 MB) aliases zpart (4.19 MB); lifetimes disjoint
    float* fmpart = zpart;

    k_prep2<<<dim3(B, 7), 256, 0, stream>>>(X, w_a, b_a, Xb, fscore, fmpart);
    k_mred<<<B, 256, 0, stream>>>(fmpart, fmb);
    k_castw<<<512, 256, 0, stream>>>(word, wordb);
    k_trW<<<dim3(16, 32, 3), 256, 0, stream>>>(k_w, r_w, WcatT);
    k_trI<<<dim3(16, 8, 2), 256, 0, stream>>>(w_h, w_c, wiT);
    k_init_gemm<<<8, 256, 0, stream>>>(fmb, wiT, b_h, b_c, Abuf, cb0);

    // c_t lives in cb[t&1]; init wrote cb0 (= c_0)
    float* cb[2] = {cb0, cb1};
    k_step4<<<dim3(B, 4), 256, 0, stream>>>(zpart, bias, cb0, cb1, Abuf, Xb,
                                            fscore, w_a_h, out_h, out_m, out_a, 0);
    for (int t = 0; t < T; ++t) {
        k_gemm32<<<512, 256, 0, stream>>>(Abuf, wordb, WcatT, zpart, t);
        k_step4<<<dim3(B, 4), 256, 0, stream>>>(zpart, bias, cb[t & 1], cb[(t + 1) & 1],
                                                Abuf, Xb, fscore, w_a_h,
                                                out_h, out_m, out_a, t + 1);
    }
}

// Round 12
// 510.691 us; speedup vs baseline: 7.5092x; 1.0881x over previous
//
#include <hip/hip_runtime.h>
#include <math.h>

#define B  128
#define L  196
#define F2 512
#define T  32
#define D  256
#define H  512
#define H4 2048
#define KCAT 1280
#define KS 4
#define KCHUNK 320   // KCAT/KS

typedef __attribute__((ext_vector_type(8))) short bf16x8;
typedef __attribute__((ext_vector_type(4))) float f32x4;

__device__ __forceinline__ float sigf(float x) { return 1.0f / (1.0f + expf(-x)); }
__device__ __forceinline__ unsigned short f2bf(float x) {
    unsigned u = __float_as_uint(x);
    u += 0x7FFF + ((u >> 16) & 1);
    return (unsigned short)(u >> 16);
}
__device__ __forceinline__ float bf2f(unsigned short s) {
    return __uint_as_float(((unsigned)s) << 16);
}
__device__ __forceinline__ float wred_sum(float v) {
    for (int o = 32; o > 0; o >>= 1) v += __shfl_down(v, o);
    return v;
}

// ---------- setup (all verified round 5/7/9) ----------

__global__ void k_prep2(const float* __restrict__ X, const float* __restrict__ w_a,
                        const float* __restrict__ b_a, unsigned short* __restrict__ Xb,
                        float* __restrict__ fscore, float* __restrict__ fmpart) {
    __shared__ float sp[8][512];
    int b = blockIdx.x, g = blockIdx.y, tid = threadIdx.x;
    int rowi = tid >> 5, lane32 = tid & 31;
    int f0 = tid * 2;
    float2 acc = make_float2(0.f, 0.f);
    for (int s = 0; s < 4; ++s) {
        int li = s * 8 + rowi;
        float4 part[4];
        if (li < 28) {
            size_t row = (size_t)b * L + g * 28 + li;
            const float* src = X + row * F2;
            unsigned short* dst = Xb + row * F2;
            float sc = 0.f;
            #pragma unroll
            for (int j = 0; j < 4; ++j) {
                int f = j * 128 + lane32 * 4;
                float4 v = *(const float4*)(src + f);
                float4 w = *(const float4*)(w_a + f);
                sc += v.x * w.x + v.y * w.y + v.z * w.z + v.w * w.w;
                part[j] = v;
                ushort4 u;
                u.x = f2bf(v.x); u.y = f2bf(v.y); u.z = f2bf(v.z); u.w = f2bf(v.w);
                *(ushort4*)(dst + f) = u;
            }
            for (int o = 16; o > 0; o >>= 1) sc += __shfl_down(sc, o, 32);
            if (lane32 == 0) fscore[row] = sc + b_a[0];
        } else {
            #pragma unroll
            for (int j = 0; j < 4; ++j) part[j] = make_float4(0.f, 0.f, 0.f, 0.f);
        }
        __syncthreads();
        #pragma unroll
        for (int j = 0; j < 4; ++j)
            *(float4*)&sp[rowi][j * 128 + lane32 * 4] = part[j];
        __syncthreads();
        #pragma unroll
        for (int r = 0; r < 8; ++r) { acc.x += sp[r][f0]; acc.y += sp[r][f0 + 1]; }
    }
    *(float2*)&fmpart[((size_t)b * 7 + g) * 512 + f0] = acc;
}

__global__ void k_mred(const float* __restrict__ fmpart, unsigned short* __restrict__ fmb) {
    int b = blockIdx.x, tid = threadIdx.x;
    int f0 = tid * 2;
    float2 acc = make_float2(0.f, 0.f);
    #pragma unroll
    for (int g = 0; g < 7; ++g) {
        float2 v = *(const float2*)&fmpart[((size_t)b * 7 + g) * 512 + f0];
        acc.x += v.x; acc.y += v.y;
    }
    ushort2 u; u.x = f2bf(acc.x * (1.0f / L)); u.y = f2bf(acc.y * (1.0f / L));
    *(ushort2*)(fmb + (size_t)b * F2 + f0) = u;
}

__global__ void k_castw(const float* __restrict__ src, unsigned short* __restrict__ dst) {
    size_t i = ((size_t)blockIdx.x * 256 + threadIdx.x) * 8;
    float4 v0 = *(const float4*)(src + i);
    float4 v1 = *(const float4*)(src + i + 4);
    ushort4 u0, u1;
    u0.x = f2bf(v0.x); u0.y = f2bf(v0.y); u0.z = f2bf(v0.z); u0.w = f2bf(v0.w);
    u1.x = f2bf(v1.x); u1.y = f2bf(v1.y); u1.z = f2bf(v1.z); u1.w = f2bf(v1.w);
    *(ushort4*)(dst + i) = u0;
    *(ushort4*)(dst + i + 4) = u1;
}

__global__ void k_trW(const float* __restrict__ k_w, const float* __restrict__ r_w,
                      unsigned short* __restrict__ WcatT) {
    int job = blockIdx.z;
    if (job == 2 && blockIdx.x >= 8) return;
    const float* src; int colOff;
    if (job == 0)      { src = k_w + (size_t)256 * H4; colOff = 0; }
    else if (job == 1) { src = r_w;                    colOff = 512; }
    else               { src = k_w;                    colOff = 1024; }
    __shared__ float Ls[32][65];
    int r0 = blockIdx.x * 32, c0 = blockIdx.y * 64;
    int tid = threadIdx.x;
    int r = tid >> 3, c8 = (tid & 7) * 8;
    const float* s = src + (size_t)(r0 + r) * H4 + c0 + c8;
    #pragma unroll
    for (int j = 0; j < 8; ++j) Ls[r][c8 + j] = s[j];
    __syncthreads();
    int cc = tid >> 2, q = tid & 3;
    unsigned short tmp[8];
    #pragma unroll
    for (int j = 0; j < 8; ++j) tmp[j] = f2bf(Ls[q * 8 + j][cc]);
    *(float4*)(WcatT + (size_t)(c0 + cc) * KCAT + colOff + r0 + q * 8) = *(float4*)tmp;
}

__global__ void k_trI(const float* __restrict__ w_h, const float* __restrict__ w_c,
                      unsigned short* __restrict__ wiT) {
    int job = blockIdx.z;
    const float* src = job ? w_c : w_h;
    unsigned short* dst = wiT + (size_t)job * 512 * 512;
    __shared__ float Ls[32][65];
    int r0 = blockIdx.x * 32, c0 = blockIdx.y * 64;
    int tid = threadIdx.x;
    int r = tid >> 3, c8 = (tid & 7) * 8;
    const float* s = src + (size_t)(r0 + r) * 512 + c0 + c8;
    #pragma unroll
    for (int j = 0; j < 8; ++j) Ls[r][c8 + j] = s[j];
    __syncthreads();
    int cc = tid >> 2, q = tid & 3;
    unsigned short tmp[8];
    #pragma unroll
    for (int j = 0; j < 8; ++j) tmp[j] = f2bf(Ls[q * 8 + j][cc]);
    *(float4*)(dst + (size_t)(c0 + cc) * 512 + r0 + q * 8) = *(float4*)tmp;
}

// ---------- init-state GEMM (MFMA, verified) ----------
__global__ __launch_bounds__(256) void k_init_gemm(
    const unsigned short* __restrict__ A, const unsigned short* __restrict__ Bt,
    const float* __restrict__ b_h, const float* __restrict__ b_c,
    unsigned short* __restrict__ Abuf0, float* __restrict__ cbuf) {
    __shared__ short As[128 * 64];
    __shared__ short Bs[128 * 64];
    int tid = threadIdx.x;
    int nbase = blockIdx.x * 128;
    int wave = tid >> 6, lane = tid & 63;
    int wm = (wave >> 1) * 64, wn = (wave & 1) * 64;
    int l15 = lane & 15, l4 = lane >> 4;

    f32x4 acc[4][4];
    #pragma unroll
    for (int i = 0; i < 4; ++i)
        #pragma unroll
        for (int j = 0; j < 4; ++j) acc[i][j] = (f32x4){0.f, 0.f, 0.f, 0.f};

    for (int it = 0; it < 8; ++it) {
        int kbase = it * 64;
        #pragma unroll
        for (int ch = 0; ch < 4; ++ch) {
            int idx = ch * 256 + tid;
            int row = idx >> 3, q = idx & 7;
            int k = kbase + q * 8;
            float4 v = *(const float4*)(A + (size_t)row * 512 + k);
            *(float4*)&As[row * 64 + ((q ^ (row & 7)) << 3)] = v;
            float4 w = *(const float4*)(Bt + (size_t)(nbase + row) * 512 + k);
            *(float4*)&Bs[row * 64 + ((q ^ (row & 7)) << 3)] = w;
        }
        __syncthreads();
        #pragma unroll
        for (int ks = 0; ks < 2; ++ks) {
            bf16x8 a[4], b[4];
            #pragma unroll
            for (int f = 0; f < 4; ++f) {
                int ar = wm + f * 16 + l15;
                int q = ks * 4 + l4;
                a[f] = *(const bf16x8*)&As[ar * 64 + ((q ^ (ar & 7)) << 3)];
                int br = wn + f * 16 + l15;
                b[f] = *(const bf16x8*)&Bs[br * 64 + ((q ^ (br & 7)) << 3)];
            }
            #pragma unroll
            for (int fm = 0; fm < 4; ++fm)
                #pragma unroll
                for (int fn = 0; fn < 4; ++fn)
                    acc[fm][fn] = __builtin_amdgcn_mfma_f32_16x16x32_bf16(a[fm], b[fn], acc[fm][fn], 0, 0, 0);
        }
        __syncthreads();
    }
    #pragma unroll
    for (int fm = 0; fm < 4; ++fm)
        #pragma unroll
        for (int j = 0; j < 4; ++j) {
            int m = wm + fm * 16 + l4 * 4 + j;
            #pragma unroll
            for (int fn = 0; fn < 4; ++fn) {
                int gn = nbase + wn + fn * 16 + l15;
                float v = acc[fm][fn][j];
                if (gn < 512) Abuf0[(size_t)m * 1024 + 512 + gn] = f2bf(tanhf(v + b_h[gn]));
                else          cbuf[(size_t)m * 512 + gn - 512] = tanhf(v + b_c[gn - 512]);
            }
        }
}

// ---------- per-step gates GEMM: 64x32 tiles, 512 blocks (byte-exact r9) ----------
__global__ __launch_bounds__(256) void k_gemm32(
    const unsigned short* __restrict__ Abuf, const unsigned short* __restrict__ wordb,
    const unsigned short* __restrict__ WcatT, float* __restrict__ zpart, int t) {
    __shared__ short As[64 * 64];
    __shared__ short Bs[32 * 64];
    int tid = threadIdx.x;
    int bid = blockIdx.x;
    int ksb = bid >> 7, rem = bid & 127;
    int rowbase = (rem >> 6) * 64, nbase = (rem & 63) * 32;
    int wave = tid >> 6, lane = tid & 63;
    int wm = (wave & 1) * 32, wn = (wave >> 1) * 16;
    int l15 = lane & 15, l4 = lane >> 4;

    f32x4 acc[2];
    acc[0] = (f32x4){0.f, 0.f, 0.f, 0.f};
    acc[1] = (f32x4){0.f, 0.f, 0.f, 0.f};

    for (int it = 0; it < KCHUNK / 64; ++it) {
        int kbase = ksb * KCHUNK + it * 64;
        #pragma unroll
        for (int p = 0; p < 2; ++p) {
            int idx = p * 256 + tid;
            int row = idx >> 3, q = idx & 7;
            int k = kbase + q * 8;
            int gr = rowbase + row;
            float4 v;
            if (k < 1024) v = *(const float4*)(Abuf + (size_t)gr * 1024 + k);
            else          v = *(const float4*)(wordb + ((size_t)gr * T + t) * D + (k - 1024));
            *(float4*)&As[row * 64 + ((q ^ (row & 7)) << 3)] = v;
        }
        {
            int row = tid >> 3, q = tid & 7;
            float4 w = *(const float4*)(WcatT + (size_t)(nbase + row) * KCAT + kbase + q * 8);
            *(float4*)&Bs[row * 64 + ((q ^ (row & 7)) << 3)] = w;
        }
        __syncthreads();
        #pragma unroll
        for (int ks2 = 0; ks2 < 2; ++ks2) {
            int q = ks2 * 4 + l4;
            bf16x8 a[2], bb;
            #pragma unroll
            for (int fm = 0; fm < 2; ++fm) {
                int ar = wm + fm * 16 + l15;
                a[fm] = *(const bf16x8*)&As[ar * 64 + ((q ^ (ar & 7)) << 3)];
            }
            {
                int br = wn + l15;
                bb = *(const bf16x8*)&Bs[br * 64 + ((q ^ (br & 7)) << 3)];
            }
            #pragma unroll
            for (int fm = 0; fm < 2; ++fm)
                acc[fm] = __builtin_amdgcn_mfma_f32_16x16x32_bf16(a[fm], bb, acc[fm], 0, 0, 0);
        }
        __syncthreads();
    }
    float* zp = zpart + (size_t)ksb * B * H4;
    #pragma unroll
    for (int fm = 0; fm < 2; ++fm)
        #pragma unroll
        for (int j = 0; j < 4; ++j) {
            int m = rowbase + wm + fm * 16 + l4 * 4 + j;
            zp[(size_t)m * H4 + nbase + wn + l15] = acc[fm][j];
        }
}

// ---------- fused cell + attention. grid (B, 4), 256 thr ----------
// r9 body with ONE isolated change: softmax without max-subtraction.
// score = tanh(.) in [-1,1] -> exp in [0.37, 2.72]; shift-invariant, identical result.
__global__ __launch_bounds__(256) void k_step4(
    const float* __restrict__ zpart, const float* __restrict__ bias,
    const float* __restrict__ cb_cur, float* __restrict__ cb_nxt,
    unsigned short* __restrict__ Abuf,
    const unsigned short* __restrict__ Xb, const float* __restrict__ fscore,
    const float* __restrict__ w_a_h,
    float* __restrict__ out_h, float* __restrict__ out_m, float* __restrict__ out_a,
    int t_next) {
    __shared__ float red[8];
    __shared__ float sal[200];
    __shared__ float sp2[4][64][2];
    int b = blockIdx.x, quarter = blockIdx.y, tid = threadIdx.x;
    int lane = tid & 63, wid = tid >> 6;
    int n0 = tid * 2;
    float hp;
    if (t_next > 0) {
        float2 z[4];
        #pragma unroll
        for (int g = 0; g < 4; ++g) z[g] = *(const float2*)(bias + g * H + n0);
        #pragma unroll
        for (int ks = 0; ks < KS; ++ks) {
            const float* zp = zpart + ((size_t)ks * B + b) * H4;
            #pragma unroll
            for (int g = 0; g < 4; ++g) {
                float2 v = *(const float2*)(zp + g * H + n0);
                z[g].x += v.x; z[g].y += v.y;
            }
        }
        float2 cv = *(const float2*)(cb_cur + (size_t)b * H + n0);
        float cnx = sigf(z[1].x) * cv.x + sigf(z[0].x) * tanhf(z[2].x);
        float cny = sigf(z[1].y) * cv.y + sigf(z[0].y) * tanhf(z[2].y);
        float hnx = sigf(z[3].x) * tanhf(cnx);
        float hny = sigf(z[3].y) * tanhf(cny);
        if (quarter == 0) {
            int tp = t_next - 1;
            *(float2*)(cb_nxt + (size_t)b * H + n0) = make_float2(cnx, cny);
            *(float2*)(out_m + ((size_t)tp * B + b) * H + n0) = make_float2(cnx, cny);
            *(float2*)(out_h + ((size_t)b * T + tp) * H + n0) = make_float2(hnx, hny);
            ushort2 hu; hu.x = f2bf(hnx); hu.y = f2bf(hny);
            *(ushort2*)(Abuf + (size_t)b * 1024 + 512 + n0) = hu;
        }
        hp = hnx * w_a_h[n0] + hny * w_a_h[n0 + 1];
    } else {
        ushort2 hu = *(const ushort2*)(Abuf + (size_t)b * 1024 + 512 + n0);
        hp = bf2f(hu.x) * w_a_h[n0] + bf2f(hu.y) * w_a_h[n0 + 1];
    }
    if (t_next >= T) return;

    float s = wred_sum(hp);
    if (lane == 0) red[wid] = s;
    __syncthreads();
    float hs = red[0] + red[1] + red[2] + red[3];
    float scv = (tid < L) ? tanhf(hs + fscore[b * L + tid]) : 0.f;
    float ex = (tid < L) ? expf(scv) : 0.f;   // bounded: scv in [-1,1]
    float es = wred_sum(ex);
    if (lane == 0) red[4 + wid] = es;
    __syncthreads();
    float denom = red[4] + red[5] + red[6] + red[7];
    float al = ex / denom;
    if (tid < L) {
        sal[tid] = al;
        if (quarter == 0) out_a[((size_t)b * T + t_next) * L + tid] = al;
    }
    __syncthreads();

    int fi = tid & 63, lg = tid >> 6;
    const unsigned* xb32 = (const unsigned*)(Xb + (size_t)b * L * F2) + quarter * 64 + fi;
    int l0 = lg * 49;
    float a0 = 0.f, a1 = 0.f;
    for (int sblk = 0; sblk < 49; sblk += 7) {
        unsigned u[7];
        #pragma unroll
        for (int j = 0; j < 7; ++j) u[j] = xb32[(size_t)(l0 + sblk + j) * 256];
        #pragma unroll
        for (int j = 0; j < 7; ++j) {
            float w = sal[l0 + sblk + j];
            a0 += bf2f((unsigned short)(u[j] & 0xFFFF)) * w;
            a1 += bf2f((unsigned short)(u[j] >> 16)) * w;
        }
    }
    sp2[lg][fi][0] = a0; sp2[lg][fi][1] = a1;
    __syncthreads();
    if (tid < 64) {
        ushort2 cu;
        cu.x = f2bf(sp2[0][tid][0] + sp2[1][tid][0] + sp2[2][tid][0] + sp2[3][tid][0]);
        cu.y = f2bf(sp2[0][tid][1] + sp2[1][tid][1] + sp2[2][tid][1] + sp2[3][tid][1]);
        *(ushort2*)(Abuf + (size_t)b * 1024 + (quarter * 64 + tid) * 2) = cu;
    }
}

extern "C" void kernel_launch(void* const* d_in, const int* in_sizes, int n_in,
                              void* d_out, int out_size, void* d_ws, size_t ws_size,
                              hipStream_t stream) {
    (void)in_sizes; (void)n_in; (void)out_size; (void)ws_size;
    const float* X     = (const float*)d_in[0];
    const float* word  = (const float*)d_in[1];
    const float* w_h   = (const float*)d_in[2];
    const float* b_h   = (const float*)d_in[3];
    const float* w_c   = (const float*)d_in[4];
    const float* b_c   = (const float*)d_in[5];
    const float* w_a_h = (const float*)d_in[6];
    const float* w_a   = (const float*)d_in[7];
    const float* b_a   = (const float*)d_in[8];
    const float* k_w   = (const float*)d_in[9];
    const float* r_w   = (const float*)d_in[10];
    const float* bias  = (const float*)d_in[11];

    float* out_h = (float*)d_out;
    float* out_m = out_h + (size_t)B * T * H;
    float* out_a = out_m + (size_t)T * B * H;

    // ws layout — total 39,290,880 bytes (proven footprint)
    char* p = (char*)d_ws;
    unsigned short* Xb    = (unsigned short*)p; p += (size_t)B * L * F2 * 2;
    unsigned short* WcatT = (unsigned short*)p; p += (size_t)H4 * KCAT * 2;
    unsigned short* wiT   = (unsigned short*)p; p += (size_t)1024 * 512 * 2;
    unsigned short* wordb = (unsigned short*)p; p += (size_t)B * T * D * 2;
    unsigned short* fmb   = (unsigned short*)p; p += (size_t)B * F2 * 2;
    unsigned short* Abuf  = (unsigned short*)p; p += (size_t)B * 1024 * 2;
    float* fscore = (float*)p; p += (size_t)B * L * 4;
    float* cb0    = (float*)p; p += (size_t)B * H * 4;
    float* cb1    = (float*)p; p += (size_t)B * H * 4;
    float* zpart  = (float*)p; p += (size_t)KS * B * H4 * 4;
    // fmpart (B*7*512 fp32 = 1.84 MB) aliases zpart (4.19 MB); lifetimes disjoint
    float* fmpart = zpart;

    k_prep2<<<dim3(B, 7), 256, 0, stream>>>(X, w_a, b_a, Xb, fscore, fmpart);
    k_mred<<<B, 256, 0, stream>>>(fmpart, fmb);
    k_castw<<<512, 256, 0, stream>>>(word, wordb);
    k_trW<<<dim3(16, 32, 3), 256, 0, stream>>>(k_w, r_w, WcatT);
    k_trI<<<dim3(16, 8, 2), 256, 0, stream>>>(w_h, w_c, wiT);
    k_init_gemm<<<8, 256, 0, stream>>>(fmb, wiT, b_h, b_c, Abuf, cb0);

    // c_t lives in cb[t&1]; init wrote cb0 (= c_0)
    float* cb[2] = {cb0, cb1};
    k_step4<<<dim3(B, 4), 256, 0, stream>>>(zpart, bias, cb0, cb1, Abuf, Xb,
                                            fscore, w_a_h, out_h, out_m, out_a, 0);
    for (int t = 0; t < T; ++t) {
        k_gemm32<<<512, 256, 0, stream>>>(Abuf, wordb, WcatT, zpart, t);
        k_step4<<<dim3(B, 4), 256, 0, stream>>>(zpart, bias, cb[t & 1], cb[(t + 1) & 1],
                                                Abuf, Xb, fscore, w_a_h,
                                                out_h, out_m, out_a, t + 1);
    }
}

// Round 13
// 461.238 us; speedup vs baseline: 8.3143x; 1.1072x over previous
//
#include <hip/hip_runtime.h>
#include <math.h>

#define B  128
#define L  196
#define F2 512
#define T  32
#define D  256
#define H  512
#define H4 2048
#define KCAT 1024     // ctx(512) + h(512); word part precomputed
#define KS 4
#define KCHUNK 256    // KCAT/KS

typedef __attribute__((ext_vector_type(8))) short bf16x8;
typedef __attribute__((ext_vector_type(4))) float f32x4;

__device__ __forceinline__ float sigf(float x) { return 1.0f / (1.0f + expf(-x)); }
__device__ __forceinline__ unsigned short f2bf(float x) {
    unsigned u = __float_as_uint(x);
    u += 0x7FFF + ((u >> 16) & 1);
    return (unsigned short)(u >> 16);
}
__device__ __forceinline__ float bf2f(unsigned short s) {
    return __uint_as_float(((unsigned)s) << 16);
}
__device__ __forceinline__ float wred_sum(float v) {
    for (int o = 32; o > 0; o >>= 1) v += __shfl_down(v, o);
    return v;
}

// ---------- setup ----------

__global__ void k_prep2(const float* __restrict__ X, const float* __restrict__ w_a,
                        const float* __restrict__ b_a, unsigned short* __restrict__ Xb,
                        float* __restrict__ fscore, float* __restrict__ fmpart) {
    __shared__ float sp[8][512];
    int b = blockIdx.x, g = blockIdx.y, tid = threadIdx.x;
    int rowi = tid >> 5, lane32 = tid & 31;
    int f0 = tid * 2;
    float2 acc = make_float2(0.f, 0.f);
    for (int s = 0; s < 4; ++s) {
        int li = s * 8 + rowi;
        float4 part[4];
        if (li < 28) {
            size_t row = (size_t)b * L + g * 28 + li;
            const float* src = X + row * F2;
            unsigned short* dst = Xb + row * F2;
            float sc = 0.f;
            #pragma unroll
            for (int j = 0; j < 4; ++j) {
                int f = j * 128 + lane32 * 4;
                float4 v = *(const float4*)(src + f);
                float4 w = *(const float4*)(w_a + f);
                sc += v.x * w.x + v.y * w.y + v.z * w.z + v.w * w.w;
                part[j] = v;
                ushort4 u;
                u.x = f2bf(v.x); u.y = f2bf(v.y); u.z = f2bf(v.z); u.w = f2bf(v.w);
                *(ushort4*)(dst + f) = u;
            }
            for (int o = 16; o > 0; o >>= 1) sc += __shfl_down(sc, o, 32);
            if (lane32 == 0) fscore[row] = sc + b_a[0];
        } else {
            #pragma unroll
            for (int j = 0; j < 4; ++j) part[j] = make_float4(0.f, 0.f, 0.f, 0.f);
        }
        __syncthreads();
        #pragma unroll
        for (int j = 0; j < 4; ++j)
            *(float4*)&sp[rowi][j * 128 + lane32 * 4] = part[j];
        __syncthreads();
        #pragma unroll
        for (int r = 0; r < 8; ++r) { acc.x += sp[r][f0]; acc.y += sp[r][f0 + 1]; }
    }
    *(float2*)&fmpart[((size_t)b * 7 + g) * 512 + f0] = acc;
}

__global__ void k_mred(const float* __restrict__ fmpart, unsigned short* __restrict__ fmb) {
    int b = blockIdx.x, tid = threadIdx.x;
    int f0 = tid * 2;
    float2 acc = make_float2(0.f, 0.f);
    #pragma unroll
    for (int g = 0; g < 7; ++g) {
        float2 v = *(const float2*)&fmpart[((size_t)b * 7 + g) * 512 + f0];
        acc.x += v.x; acc.y += v.y;
    }
    ushort2 u; u.x = f2bf(acc.x * (1.0f / L)); u.y = f2bf(acc.y * (1.0f / L));
    *(ushort2*)(fmb + (size_t)b * F2 + f0) = u;
}

// transpose-cast: job0 k_w[256:768]->WcatT cols 0..511; job1 r_w->WcatT cols 512..1023;
// job2 k_w[0:256]->wT [2048][256]. grid (16, 32, 3); job2 uses x<8 only.
__global__ void k_trW(const float* __restrict__ k_w, const float* __restrict__ r_w,
                      unsigned short* __restrict__ WcatT, unsigned short* __restrict__ wT) {
    int job = blockIdx.z;
    if (job == 2 && blockIdx.x >= 8) return;
    const float* src; unsigned short* dstBase; int dstLD, colOff;
    if (job == 0)      { src = k_w + (size_t)256 * H4; dstBase = WcatT; dstLD = KCAT; colOff = 0; }
    else if (job == 1) { src = r_w;                    dstBase = WcatT; dstLD = KCAT; colOff = 512; }
    else               { src = k_w;                    dstBase = wT;    dstLD = 256;  colOff = 0; }
    __shared__ float Ls[32][65];
    int r0 = blockIdx.x * 32, c0 = blockIdx.y * 64;
    int tid = threadIdx.x;
    int r = tid >> 3, c8 = (tid & 7) * 8;
    const float* s = src + (size_t)(r0 + r) * H4 + c0 + c8;
    #pragma unroll
    for (int j = 0; j < 8; ++j) Ls[r][c8 + j] = s[j];
    __syncthreads();
    int cc = tid >> 2, q = tid & 3;
    unsigned short tmp[8];
    #pragma unroll
    for (int j = 0; j < 8; ++j) tmp[j] = f2bf(Ls[q * 8 + j][cc]);
    *(float4*)(dstBase + (size_t)(c0 + cc) * dstLD + colOff + r0 + q * 8) = *(float4*)tmp;
}

__global__ void k_trI(const float* __restrict__ w_h, const float* __restrict__ w_c,
                      unsigned short* __restrict__ wiT) {
    int job = blockIdx.z;
    const float* src = job ? w_c : w_h;
    unsigned short* dst = wiT + (size_t)job * 512 * 512;
    __shared__ float Ls[32][65];
    int r0 = blockIdx.x * 32, c0 = blockIdx.y * 64;
    int tid = threadIdx.x;
    int r = tid >> 3, c8 = (tid & 7) * 8;
    const float* s = src + (size_t)(r0 + r) * 512 + c0 + c8;
    #pragma unroll
    for (int j = 0; j < 8; ++j) Ls[r][c8 + j] = s[j];
    __syncthreads();
    int cc = tid >> 2, q = tid & 3;
    unsigned short tmp[8];
    #pragma unroll
    for (int j = 0; j < 8; ++j) tmp[j] = f2bf(Ls[q * 8 + j][cc]);
    *(float4*)(dst + (size_t)(c0 + cc) * 512 + r0 + q * 8) = *(float4*)tmp;
}

// ---------- init-state GEMM (MFMA, verified) ----------
__global__ __launch_bounds__(256) void k_init_gemm(
    const unsigned short* __restrict__ A, const unsigned short* __restrict__ Bt,
    const float* __restrict__ b_h, const float* __restrict__ b_c,
    unsigned short* __restrict__ Abuf0, float* __restrict__ cbuf) {
    __shared__ short As[128 * 64];
    __shared__ short Bs[128 * 64];
    int tid = threadIdx.x;
    int nbase = blockIdx.x * 128;
    int wave = tid >> 6, lane = tid & 63;
    int wm = (wave >> 1) * 64, wn = (wave & 1) * 64;
    int l15 = lane & 15, l4 = lane >> 4;

    f32x4 acc[4][4];
    #pragma unroll
    for (int i = 0; i < 4; ++i)
        #pragma unroll
        for (int j = 0; j < 4; ++j) acc[i][j] = (f32x4){0.f, 0.f, 0.f, 0.f};

    for (int it = 0; it < 8; ++it) {
        int kbase = it * 64;
        #pragma unroll
        for (int ch = 0; ch < 4; ++ch) {
            int idx = ch * 256 + tid;
            int row = idx >> 3, q = idx & 7;
            int k = kbase + q * 8;
            float4 v = *(const float4*)(A + (size_t)row * 512 + k);
            *(float4*)&As[row * 64 + ((q ^ (row & 7)) << 3)] = v;
            float4 w = *(const float4*)(Bt + (size_t)(nbase + row) * 512 + k);
            *(float4*)&Bs[row * 64 + ((q ^ (row & 7)) << 3)] = w;
        }
        __syncthreads();
        #pragma unroll
        for (int ks = 0; ks < 2; ++ks) {
            bf16x8 a[4], b[4];
            #pragma unroll
            for (int f = 0; f < 4; ++f) {
                int ar = wm + f * 16 + l15;
                int q = ks * 4 + l4;
                a[f] = *(const bf16x8*)&As[ar * 64 + ((q ^ (ar & 7)) << 3)];
                int br = wn + f * 16 + l15;
                b[f] = *(const bf16x8*)&Bs[br * 64 + ((q ^ (br & 7)) << 3)];
            }
            #pragma unroll
            for (int fm = 0; fm < 4; ++fm)
                #pragma unroll
                for (int fn = 0; fn < 4; ++fn)
                    acc[fm][fn] = __builtin_amdgcn_mfma_f32_16x16x32_bf16(a[fm], b[fn], acc[fm][fn], 0, 0, 0);
        }
        __syncthreads();
    }
    #pragma unroll
    for (int fm = 0; fm < 4; ++fm)
        #pragma unroll
        for (int j = 0; j < 4; ++j) {
            int m = wm + fm * 16 + l4 * 4 + j;
            #pragma unroll
            for (int fn = 0; fn < 4; ++fn) {
                int gn = nbase + wn + fn * 16 + l15;
                float v = acc[fm][fn][j];
                if (gn < 512) Abuf0[(size_t)m * 1024 + 512 + gn] = f2bf(tanhf(v + b_h[gn]));
                else          cbuf[(size_t)m * 512 + gn - 512] = tanhf(v + b_c[gn - 512]);
            }
        }
}

// ---------- one-time word GEMM: wpart[B*T][2048] = bf16(word) @ wT^T ----------
// M=4096, K=256, N=2048. grid (16 n-tiles, 32 m-tiles), 128x128 tile (init_gemm shape).
__global__ __launch_bounds__(256) void k_wgemm(
    const float* __restrict__ word,           // [4096][256] fp32
    const unsigned short* __restrict__ wT,    // [2048][256] bf16
    float* __restrict__ wpart) {              // [4096][2048] fp32
    __shared__ short As[128 * 64];
    __shared__ short Bs[128 * 64];
    int tid = threadIdx.x;
    int nbase = blockIdx.x * 128;
    int mbase = blockIdx.y * 128;
    int wave = tid >> 6, lane = tid & 63;
    int wm = (wave >> 1) * 64, wn = (wave & 1) * 64;
    int l15 = lane & 15, l4 = lane >> 4;

    f32x4 acc[4][4];
    #pragma unroll
    for (int i = 0; i < 4; ++i)
        #pragma unroll
        for (int j = 0; j < 4; ++j) acc[i][j] = (f32x4){0.f, 0.f, 0.f, 0.f};

    for (int it = 0; it < 4; ++it) {
        int kbase = it * 64;
        #pragma unroll
        for (int ch = 0; ch < 4; ++ch) {
            int idx = ch * 256 + tid;
            int row = idx >> 3, q = idx & 7;
            int k = kbase + q * 8;
            // A: word fp32 -> bf16 inline (identical values to the old k_castw path)
            const float* ap = word + (size_t)(mbase + row) * 256 + k;
            float4 v0 = *(const float4*)ap;
            float4 v1 = *(const float4*)(ap + 4);
            unsigned short tmp[8];
            tmp[0] = f2bf(v0.x); tmp[1] = f2bf(v0.y); tmp[2] = f2bf(v0.z); tmp[3] = f2bf(v0.w);
            tmp[4] = f2bf(v1.x); tmp[5] = f2bf(v1.y); tmp[6] = f2bf(v1.z); tmp[7] = f2bf(v1.w);
            *(float4*)&As[row * 64 + ((q ^ (row & 7)) << 3)] = *(float4*)tmp;
            float4 w = *(const float4*)(wT + (size_t)(nbase + row) * 256 + k);
            *(float4*)&Bs[row * 64 + ((q ^ (row & 7)) << 3)] = w;
        }
        __syncthreads();
        #pragma unroll
        for (int ks = 0; ks < 2; ++ks) {
            bf16x8 a[4], b[4];
            #pragma unroll
            for (int f = 0; f < 4; ++f) {
                int ar = wm + f * 16 + l15;
                int q = ks * 4 + l4;
                a[f] = *(const bf16x8*)&As[ar * 64 + ((q ^ (ar & 7)) << 3)];
                int br = wn + f * 16 + l15;
                b[f] = *(const bf16x8*)&Bs[br * 64 + ((q ^ (br & 7)) << 3)];
            }
            #pragma unroll
            for (int fm = 0; fm < 4; ++fm)
                #pragma unroll
                for (int fn = 0; fn < 4; ++fn)
                    acc[fm][fn] = __builtin_amdgcn_mfma_f32_16x16x32_bf16(a[fm], b[fn], acc[fm][fn], 0, 0, 0);
        }
        __syncthreads();
    }
    #pragma unroll
    for (int fm = 0; fm < 4; ++fm)
        #pragma unroll
        for (int j = 0; j < 4; ++j) {
            int m = wm + fm * 16 + l4 * 4 + j;
            #pragma unroll
            for (int fn = 0; fn < 4; ++fn)
                wpart[(size_t)(mbase + m) * H4 + nbase + wn + fn * 16 + l15] = acc[fm][fn][j];
        }
}

// ---------- per-step gates GEMM: K=1024, 64x32 tiles, 512 blocks (r9 structure, branch-free) ----------
__global__ __launch_bounds__(256) void k_gemm32(
    const unsigned short* __restrict__ Abuf,
    const unsigned short* __restrict__ WcatT,  // [2048][1024]
    float* __restrict__ zpart) {
    __shared__ short As[64 * 64];
    __shared__ short Bs[32 * 64];
    int tid = threadIdx.x;
    int bid = blockIdx.x;
    int ksb = bid >> 7, rem = bid & 127;
    int rowbase = (rem >> 6) * 64, nbase = (rem & 63) * 32;
    int wave = tid >> 6, lane = tid & 63;
    int wm = (wave & 1) * 32, wn = (wave >> 1) * 16;
    int l15 = lane & 15, l4 = lane >> 4;

    f32x4 acc[2];
    acc[0] = (f32x4){0.f, 0.f, 0.f, 0.f};
    acc[1] = (f32x4){0.f, 0.f, 0.f, 0.f};

    for (int it = 0; it < KCHUNK / 64; ++it) {
        int kbase = ksb * KCHUNK + it * 64;
        #pragma unroll
        for (int p = 0; p < 2; ++p) {
            int idx = p * 256 + tid;
            int row = idx >> 3, q = idx & 7;
            int k = kbase + q * 8;
            float4 v = *(const float4*)(Abuf + (size_t)(rowbase + row) * 1024 + k);
            *(float4*)&As[row * 64 + ((q ^ (row & 7)) << 3)] = v;
        }
        {
            int row = tid >> 3, q = tid & 7;
            float4 w = *(const float4*)(WcatT + (size_t)(nbase + row) * KCAT + kbase + q * 8);
            *(float4*)&Bs[row * 64 + ((q ^ (row & 7)) << 3)] = w;
        }
        __syncthreads();
        #pragma unroll
        for (int ks2 = 0; ks2 < 2; ++ks2) {
            int q = ks2 * 4 + l4;
            bf16x8 a[2], bb;
            #pragma unroll
            for (int fm = 0; fm < 2; ++fm) {
                int ar = wm + fm * 16 + l15;
                a[fm] = *(const bf16x8*)&As[ar * 64 + ((q ^ (ar & 7)) << 3)];
            }
            {
                int br = wn + l15;
                bb = *(const bf16x8*)&Bs[br * 64 + ((q ^ (br & 7)) << 3)];
            }
            #pragma unroll
            for (int fm = 0; fm < 2; ++fm)
                acc[fm] = __builtin_amdgcn_mfma_f32_16x16x32_bf16(a[fm], bb, acc[fm], 0, 0, 0);
        }
        __syncthreads();
    }
    float* zp = zpart + (size_t)ksb * B * H4;
    #pragma unroll
    for (int fm = 0; fm < 2; ++fm)
        #pragma unroll
        for (int j = 0; j < 4; ++j) {
            int m = rowbase + wm + fm * 16 + l4 * 4 + j;
            zp[(size_t)m * H4 + nbase + wn + l15] = acc[fm][j];
        }
}

// ---------- fused cell + attention. grid (B, 4), 256 thr (r12 body + wpart term) ----------
__global__ __launch_bounds__(256) void k_step4(
    const float* __restrict__ zpart, const float* __restrict__ wpart,
    const float* __restrict__ bias,
    const float* __restrict__ cb_cur, float* __restrict__ cb_nxt,
    unsigned short* __restrict__ Abuf,
    const unsigned short* __restrict__ Xb, const float* __restrict__ fscore,
    const float* __restrict__ w_a_h,
    float* __restrict__ out_h, float* __restrict__ out_m, float* __restrict__ out_a,
    int t_next) {
    __shared__ float red[8];
    __shared__ float sal[200];
    __shared__ float sp2[4][64][2];
    int b = blockIdx.x, quarter = blockIdx.y, tid = threadIdx.x;
    int lane = tid & 63, wid = tid >> 6;
    int n0 = tid * 2;
    float hp;
    if (t_next > 0) {
        const float* wp = wpart + ((size_t)b * T + (t_next - 1)) * H4;
        float2 z[4];
        #pragma unroll
        for (int g = 0; g < 4; ++g) {
            float2 bz = *(const float2*)(bias + g * H + n0);
            float2 wz = *(const float2*)(wp + g * H + n0);
            z[g].x = bz.x + wz.x; z[g].y = bz.y + wz.y;
        }
        #pragma unroll
        for (int ks = 0; ks < KS; ++ks) {
            const float* zp = zpart + ((size_t)ks * B + b) * H4;
            #pragma unroll
            for (int g = 0; g < 4; ++g) {
                float2 v = *(const float2*)(zp + g * H + n0);
                z[g].x += v.x; z[g].y += v.y;
            }
        }
        float2 cv = *(const float2*)(cb_cur + (size_t)b * H + n0);
        float cnx = sigf(z[1].x) * cv.x + sigf(z[0].x) * tanhf(z[2].x);
        float cny = sigf(z[1].y) * cv.y + sigf(z[0].y) * tanhf(z[2].y);
        float hnx = sigf(z[3].x) * tanhf(cnx);
        float hny = sigf(z[3].y) * tanhf(cny);
        if (quarter == 0) {
            int tp = t_next - 1;
            *(float2*)(cb_nxt + (size_t)b * H + n0) = make_float2(cnx, cny);
            *(float2*)(out_m + ((size_t)tp * B + b) * H + n0) = make_float2(cnx, cny);
            *(float2*)(out_h + ((size_t)b * T + tp) * H + n0) = make_float2(hnx, hny);
            ushort2 hu; hu.x = f2bf(hnx); hu.y = f2bf(hny);
            *(ushort2*)(Abuf + (size_t)b * 1024 + 512 + n0) = hu;
        }
        hp = hnx * w_a_h[n0] + hny * w_a_h[n0 + 1];
    } else {
        ushort2 hu = *(const ushort2*)(Abuf + (size_t)b * 1024 + 512 + n0);
        hp = bf2f(hu.x) * w_a_h[n0] + bf2f(hu.y) * w_a_h[n0 + 1];
    }
    if (t_next >= T) return;

    float s = wred_sum(hp);
    if (lane == 0) red[wid] = s;
    __syncthreads();
    float hs = red[0] + red[1] + red[2] + red[3];
    float scv = (tid < L) ? tanhf(hs + fscore[b * L + tid]) : 0.f;
    float ex = (tid < L) ? expf(scv) : 0.f;   // bounded: scv in [-1,1]
    float es = wred_sum(ex);
    if (lane == 0) red[4 + wid] = es;
    __syncthreads();
    float denom = red[4] + red[5] + red[6] + red[7];
    float al = ex / denom;
    if (tid < L) {
        sal[tid] = al;
        if (quarter == 0) out_a[((size_t)b * T + t_next) * L + tid] = al;
    }
    __syncthreads();

    int fi = tid & 63, lg = tid >> 6;
    const unsigned* xb32 = (const unsigned*)(Xb + (size_t)b * L * F2) + quarter * 64 + fi;
    int l0 = lg * 49;
    float a0 = 0.f, a1 = 0.f;
    for (int sblk = 0; sblk < 49; sblk += 7) {
        unsigned u[7];
        #pragma unroll
        for (int j = 0; j < 7; ++j) u[j] = xb32[(size_t)(l0 + sblk + j) * 256];
        #pragma unroll
        for (int j = 0; j < 7; ++j) {
            float w = sal[l0 + sblk + j];
            a0 += bf2f((unsigned short)(u[j] & 0xFFFF)) * w;
            a1 += bf2f((unsigned short)(u[j] >> 16)) * w;
        }
    }
    sp2[lg][fi][0] = a0; sp2[lg][fi][1] = a1;
    __syncthreads();
    if (tid < 64) {
        ushort2 cu;
        cu.x = f2bf(sp2[0][tid][0] + sp2[1][tid][0] + sp2[2][tid][0] + sp2[3][tid][0]);
        cu.y = f2bf(sp2[0][tid][1] + sp2[1][tid][1] + sp2[2][tid][1] + sp2[3][tid][1]);
        *(ushort2*)(Abuf + (size_t)b * 1024 + (quarter * 64 + tid) * 2) = cu;
    }
}

extern "C" void kernel_launch(void* const* d_in, const int* in_sizes, int n_in,
                              void* d_out, int out_size, void* d_ws, size_t ws_size,
                              hipStream_t stream) {
    (void)in_sizes; (void)n_in; (void)out_size; (void)ws_size;
    const float* X     = (const float*)d_in[0];
    const float* word  = (const float*)d_in[1];
    const float* w_h   = (const float*)d_in[2];
    const float* b_h   = (const float*)d_in[3];
    const float* w_c   = (const float*)d_in[4];
    const float* b_c   = (const float*)d_in[5];
    const float* w_a_h = (const float*)d_in[6];
    const float* w_a   = (const float*)d_in[7];
    const float* b_a   = (const float*)d_in[8];
    const float* k_w   = (const float*)d_in[9];
    const float* r_w   = (const float*)d_in[10];
    const float* bias  = (const float*)d_in[11];

    float* out_h = (float*)d_out;
    float* out_m = out_h + (size_t)B * T * H;
    float* out_a = out_m + (size_t)T * B * H;

    // ws layout — ~71 MB (poison fill shows ws ≈ 268 MB available)
    char* p = (char*)d_ws;
    unsigned short* Xb    = (unsigned short*)p; p += (size_t)B * L * F2 * 2;     // 25.7 MB
    unsigned short* WcatT = (unsigned short*)p; p += (size_t)H4 * KCAT * 2;      // 4.2 MB
    unsigned short* wT    = (unsigned short*)p; p += (size_t)H4 * 256 * 2;       // 1.0 MB
    unsigned short* wiT   = (unsigned short*)p; p += (size_t)1024 * 512 * 2;     // 1.0 MB
    unsigned short* fmb   = (unsigned short*)p; p += (size_t)B * F2 * 2;
    unsigned short* Abuf  = (unsigned short*)p; p += (size_t)B * 1024 * 2;
    float* fscore = (float*)p; p += (size_t)B * L * 4;
    float* cb0    = (float*)p; p += (size_t)B * H * 4;
    float* cb1    = (float*)p; p += (size_t)B * H * 4;
    float* zpart  = (float*)p; p += (size_t)KS * B * H4 * 4;                      // 4.2 MB
    float* wpart  = (float*)p; p += (size_t)B * T * H4 * 4;                       // 33.6 MB
    // fmpart (B*7*512 fp32 = 1.84 MB) aliases zpart (4.19 MB); lifetimes disjoint
    float* fmpart = zpart;

    k_prep2<<<dim3(B, 7), 256, 0, stream>>>(X, w_a, b_a, Xb, fscore, fmpart);
    k_mred<<<B, 256, 0, stream>>>(fmpart, fmb);
    k_trW<<<dim3(16, 32, 3), 256, 0, stream>>>(k_w, r_w, WcatT, wT);
    k_trI<<<dim3(16, 8, 2), 256, 0, stream>>>(w_h, w_c, wiT);
    k_wgemm<<<dim3(16, 32), 256, 0, stream>>>(word, wT, wpart);
    k_init_gemm<<<8, 256, 0, stream>>>(fmb, wiT, b_h, b_c, Abuf, cb0);

    // c_t lives in cb[t&1]; init wrote cb0 (= c_0)
    float* cb[2] = {cb0, cb1};
    k_step4<<<dim3(B, 4), 256, 0, stream>>>(zpart, wpart, bias, cb0, cb1, Abuf, Xb,
                                            fscore, w_a_h, out_h, out_m, out_a, 0);
    for (int t = 0; t < T; ++t) {
        k_gemm32<<<512, 256, 0, stream>>>(Abuf, WcatT, zpart);
        k_step4<<<dim3(B, 4), 256, 0, stream>>>(zpart, wpart, bias, cb[t & 1], cb[(t + 1) & 1],
                                                Abuf, Xb, fscore, w_a_h,
                                                out_h, out_m, out_a, t + 1);
    }
}

// Round 14
// 459.680 us; speedup vs baseline: 8.3425x; 1.0034x over previous
//
#include <hip/hip_runtime.h>
#include <math.h>

#define B  128
#define L  196
#define F2 512
#define T  32
#define D  256
#define H  512
#define H4 2048
#define KCAT 1024     // ctx(512) + h(512); word part precomputed
#define KS 4
#define KCHUNK 256    // KCAT/KS

typedef __attribute__((ext_vector_type(8))) short bf16x8;
typedef __attribute__((ext_vector_type(4))) float f32x4;

__device__ __forceinline__ float sigf(float x) { return 1.0f / (1.0f + expf(-x)); }
__device__ __forceinline__ unsigned short f2bf(float x) {
    unsigned u = __float_as_uint(x);
    u += 0x7FFF + ((u >> 16) & 1);
    return (unsigned short)(u >> 16);
}
__device__ __forceinline__ float bf2f(unsigned short s) {
    return __uint_as_float(((unsigned)s) << 16);
}
__device__ __forceinline__ float wred_sum(float v) {
    for (int o = 32; o > 0; o >>= 1) v += __shfl_down(v, o);
    return v;
}

// ---------- setup ----------

__global__ void k_prep2(const float* __restrict__ X, const float* __restrict__ w_a,
                        const float* __restrict__ b_a, unsigned short* __restrict__ Xb,
                        float* __restrict__ fscore, float* __restrict__ fmpart) {
    __shared__ float sp[8][512];
    int b = blockIdx.x, g = blockIdx.y, tid = threadIdx.x;
    int rowi = tid >> 5, lane32 = tid & 31;
    int f0 = tid * 2;
    float2 acc = make_float2(0.f, 0.f);
    for (int s = 0; s < 4; ++s) {
        int li = s * 8 + rowi;
        float4 part[4];
        if (li < 28) {
            size_t row = (size_t)b * L + g * 28 + li;
            const float* src = X + row * F2;
            unsigned short* dst = Xb + row * F2;
            float sc = 0.f;
            #pragma unroll
            for (int j = 0; j < 4; ++j) {
                int f = j * 128 + lane32 * 4;
                float4 v = *(const float4*)(src + f);
                float4 w = *(const float4*)(w_a + f);
                sc += v.x * w.x + v.y * w.y + v.z * w.z + v.w * w.w;
                part[j] = v;
                ushort4 u;
                u.x = f2bf(v.x); u.y = f2bf(v.y); u.z = f2bf(v.z); u.w = f2bf(v.w);
                *(ushort4*)(dst + f) = u;
            }
            for (int o = 16; o > 0; o >>= 1) sc += __shfl_down(sc, o, 32);
            if (lane32 == 0) fscore[row] = sc + b_a[0];
        } else {
            #pragma unroll
            for (int j = 0; j < 4; ++j) part[j] = make_float4(0.f, 0.f, 0.f, 0.f);
        }
        __syncthreads();
        #pragma unroll
        for (int j = 0; j < 4; ++j)
            *(float4*)&sp[rowi][j * 128 + lane32 * 4] = part[j];
        __syncthreads();
        #pragma unroll
        for (int r = 0; r < 8; ++r) { acc.x += sp[r][f0]; acc.y += sp[r][f0 + 1]; }
    }
    *(float2*)&fmpart[((size_t)b * 7 + g) * 512 + f0] = acc;
}

__global__ void k_mred(const float* __restrict__ fmpart, unsigned short* __restrict__ fmb) {
    int b = blockIdx.x, tid = threadIdx.x;
    int f0 = tid * 2;
    float2 acc = make_float2(0.f, 0.f);
    #pragma unroll
    for (int g = 0; g < 7; ++g) {
        float2 v = *(const float2*)&fmpart[((size_t)b * 7 + g) * 512 + f0];
        acc.x += v.x; acc.y += v.y;
    }
    ushort2 u; u.x = f2bf(acc.x * (1.0f / L)); u.y = f2bf(acc.y * (1.0f / L));
    *(ushort2*)(fmb + (size_t)b * F2 + f0) = u;
}

// transpose-cast: job0 k_w[256:768]->WcatT cols 0..511; job1 r_w->WcatT cols 512..1023;
// job2 k_w[0:256]->wT [2048][256]. grid (16, 32, 3); job2 uses x<8 only.
__global__ void k_trW(const float* __restrict__ k_w, const float* __restrict__ r_w,
                      unsigned short* __restrict__ WcatT, unsigned short* __restrict__ wT) {
    int job = blockIdx.z;
    if (job == 2 && blockIdx.x >= 8) return;
    const float* src; unsigned short* dstBase; int dstLD, colOff;
    if (job == 0)      { src = k_w + (size_t)256 * H4; dstBase = WcatT; dstLD = KCAT; colOff = 0; }
    else if (job == 1) { src = r_w;                    dstBase = WcatT; dstLD = KCAT; colOff = 512; }
    else               { src = k_w;                    dstBase = wT;    dstLD = 256;  colOff = 0; }
    __shared__ float Ls[32][65];
    int r0 = blockIdx.x * 32, c0 = blockIdx.y * 64;
    int tid = threadIdx.x;
    int r = tid >> 3, c8 = (tid & 7) * 8;
    const float* s = src + (size_t)(r0 + r) * H4 + c0 + c8;
    #pragma unroll
    for (int j = 0; j < 8; ++j) Ls[r][c8 + j] = s[j];
    __syncthreads();
    int cc = tid >> 2, q = tid & 3;
    unsigned short tmp[8];
    #pragma unroll
    for (int j = 0; j < 8; ++j) tmp[j] = f2bf(Ls[q * 8 + j][cc]);
    *(float4*)(dstBase + (size_t)(c0 + cc) * dstLD + colOff + r0 + q * 8) = *(float4*)tmp;
}

__global__ void k_trI(const float* __restrict__ w_h, const float* __restrict__ w_c,
                      unsigned short* __restrict__ wiT) {
    int job = blockIdx.z;
    const float* src = job ? w_c : w_h;
    unsigned short* dst = wiT + (size_t)job * 512 * 512;
    __shared__ float Ls[32][65];
    int r0 = blockIdx.x * 32, c0 = blockIdx.y * 64;
    int tid = threadIdx.x;
    int r = tid >> 3, c8 = (tid & 7) * 8;
    const float* s = src + (size_t)(r0 + r) * 512 + c0 + c8;
    #pragma unroll
    for (int j = 0; j < 8; ++j) Ls[r][c8 + j] = s[j];
    __syncthreads();
    int cc = tid >> 2, q = tid & 3;
    unsigned short tmp[8];
    #pragma unroll
    for (int j = 0; j < 8; ++j) tmp[j] = f2bf(Ls[q * 8 + j][cc]);
    *(float4*)(dst + (size_t)(c0 + cc) * 512 + r0 + q * 8) = *(float4*)tmp;
}

// ---------- init-state GEMM (MFMA, verified) ----------
__global__ __launch_bounds__(256) void k_init_gemm(
    const unsigned short* __restrict__ A, const unsigned short* __restrict__ Bt,
    const float* __restrict__ b_h, const float* __restrict__ b_c,
    unsigned short* __restrict__ Abuf0, float* __restrict__ cbuf) {
    __shared__ short As[128 * 64];
    __shared__ short Bs[128 * 64];
    int tid = threadIdx.x;
    int nbase = blockIdx.x * 128;
    int wave = tid >> 6, lane = tid & 63;
    int wm = (wave >> 1) * 64, wn = (wave & 1) * 64;
    int l15 = lane & 15, l4 = lane >> 4;

    f32x4 acc[4][4];
    #pragma unroll
    for (int i = 0; i < 4; ++i)
        #pragma unroll
        for (int j = 0; j < 4; ++j) acc[i][j] = (f32x4){0.f, 0.f, 0.f, 0.f};

    for (int it = 0; it < 8; ++it) {
        int kbase = it * 64;
        #pragma unroll
        for (int ch = 0; ch < 4; ++ch) {
            int idx = ch * 256 + tid;
            int row = idx >> 3, q = idx & 7;
            int k = kbase + q * 8;
            float4 v = *(const float4*)(A + (size_t)row * 512 + k);
            *(float4*)&As[row * 64 + ((q ^ (row & 7)) << 3)] = v;
            float4 w = *(const float4*)(Bt + (size_t)(nbase + row) * 512 + k);
            *(float4*)&Bs[row * 64 + ((q ^ (row & 7)) << 3)] = w;
        }
        __syncthreads();
        #pragma unroll
        for (int ks = 0; ks < 2; ++ks) {
            bf16x8 a[4], b[4];
            #pragma unroll
            for (int f = 0; f < 4; ++f) {
                int ar = wm + f * 16 + l15;
                int q = ks * 4 + l4;
                a[f] = *(const bf16x8*)&As[ar * 64 + ((q ^ (ar & 7)) << 3)];
                int br = wn + f * 16 + l15;
                b[f] = *(const bf16x8*)&Bs[br * 64 + ((q ^ (br & 7)) << 3)];
            }
            #pragma unroll
            for (int fm = 0; fm < 4; ++fm)
                #pragma unroll
                for (int fn = 0; fn < 4; ++fn)
                    acc[fm][fn] = __builtin_amdgcn_mfma_f32_16x16x32_bf16(a[fm], b[fn], acc[fm][fn], 0, 0, 0);
        }
        __syncthreads();
    }
    #pragma unroll
    for (int fm = 0; fm < 4; ++fm)
        #pragma unroll
        for (int j = 0; j < 4; ++j) {
            int m = wm + fm * 16 + l4 * 4 + j;
            #pragma unroll
            for (int fn = 0; fn < 4; ++fn) {
                int gn = nbase + wn + fn * 16 + l15;
                float v = acc[fm][fn][j];
                if (gn < 512) Abuf0[(size_t)m * 1024 + 512 + gn] = f2bf(tanhf(v + b_h[gn]));
                else          cbuf[(size_t)m * 512 + gn - 512] = tanhf(v + b_c[gn - 512]);
            }
        }
}

// ---------- one-time word GEMM: wpart[B*T][2048] = bf16(word) @ wT^T ----------
__global__ __launch_bounds__(256) void k_wgemm(
    const float* __restrict__ word,           // [4096][256] fp32
    const unsigned short* __restrict__ wT,    // [2048][256] bf16
    float* __restrict__ wpart) {              // [4096][2048] fp32
    __shared__ short As[128 * 64];
    __shared__ short Bs[128 * 64];
    int tid = threadIdx.x;
    int nbase = blockIdx.x * 128;
    int mbase = blockIdx.y * 128;
    int wave = tid >> 6, lane = tid & 63;
    int wm = (wave >> 1) * 64, wn = (wave & 1) * 64;
    int l15 = lane & 15, l4 = lane >> 4;

    f32x4 acc[4][4];
    #pragma unroll
    for (int i = 0; i < 4; ++i)
        #pragma unroll
        for (int j = 0; j < 4; ++j) acc[i][j] = (f32x4){0.f, 0.f, 0.f, 0.f};

    for (int it = 0; it < 4; ++it) {
        int kbase = it * 64;
        #pragma unroll
        for (int ch = 0; ch < 4; ++ch) {
            int idx = ch * 256 + tid;
            int row = idx >> 3, q = idx & 7;
            int k = kbase + q * 8;
            const float* ap = word + (size_t)(mbase + row) * 256 + k;
            float4 v0 = *(const float4*)ap;
            float4 v1 = *(const float4*)(ap + 4);
            unsigned short tmp[8];
            tmp[0] = f2bf(v0.x); tmp[1] = f2bf(v0.y); tmp[2] = f2bf(v0.z); tmp[3] = f2bf(v0.w);
            tmp[4] = f2bf(v1.x); tmp[5] = f2bf(v1.y); tmp[6] = f2bf(v1.z); tmp[7] = f2bf(v1.w);
            *(float4*)&As[row * 64 + ((q ^ (row & 7)) << 3)] = *(float4*)tmp;
            float4 w = *(const float4*)(wT + (size_t)(nbase + row) * 256 + k);
            *(float4*)&Bs[row * 64 + ((q ^ (row & 7)) << 3)] = w;
        }
        __syncthreads();
        #pragma unroll
        for (int ks = 0; ks < 2; ++ks) {
            bf16x8 a[4], b[4];
            #pragma unroll
            for (int f = 0; f < 4; ++f) {
                int ar = wm + f * 16 + l15;
                int q = ks * 4 + l4;
                a[f] = *(const bf16x8*)&As[ar * 64 + ((q ^ (ar & 7)) << 3)];
                int br = wn + f * 16 + l15;
                b[f] = *(const bf16x8*)&Bs[br * 64 + ((q ^ (br & 7)) << 3)];
            }
            #pragma unroll
            for (int fm = 0; fm < 4; ++fm)
                #pragma unroll
                for (int fn = 0; fn < 4; ++fn)
                    acc[fm][fn] = __builtin_amdgcn_mfma_f32_16x16x32_bf16(a[fm], b[fn], acc[fm][fn], 0, 0, 0);
        }
        __syncthreads();
    }
    #pragma unroll
    for (int fm = 0; fm < 4; ++fm)
        #pragma unroll
        for (int j = 0; j < 4; ++j) {
            int m = wm + fm * 16 + l4 * 4 + j;
            #pragma unroll
            for (int fn = 0; fn < 4; ++fn)
                wpart[(size_t)(mbase + m) * H4 + nbase + wn + fn * 16 + l15] = acc[fm][fn][j];
        }
}

// ---------- per-step gates GEMM: K=1024, 64x32 tiles, 512 blocks (byte-exact r13) ----------
__global__ __launch_bounds__(256) void k_gemm32(
    const unsigned short* __restrict__ Abuf,
    const unsigned short* __restrict__ WcatT,  // [2048][1024]
    float* __restrict__ zpart) {
    __shared__ short As[64 * 64];
    __shared__ short Bs[32 * 64];
    int tid = threadIdx.x;
    int bid = blockIdx.x;
    int ksb = bid >> 7, rem = bid & 127;
    int rowbase = (rem >> 6) * 64, nbase = (rem & 63) * 32;
    int wave = tid >> 6, lane = tid & 63;
    int wm = (wave & 1) * 32, wn = (wave >> 1) * 16;
    int l15 = lane & 15, l4 = lane >> 4;

    f32x4 acc[2];
    acc[0] = (f32x4){0.f, 0.f, 0.f, 0.f};
    acc[1] = (f32x4){0.f, 0.f, 0.f, 0.f};

    for (int it = 0; it < KCHUNK / 64; ++it) {
        int kbase = ksb * KCHUNK + it * 64;
        #pragma unroll
        for (int p = 0; p < 2; ++p) {
            int idx = p * 256 + tid;
            int row = idx >> 3, q = idx & 7;
            int k = kbase + q * 8;
            float4 v = *(const float4*)(Abuf + (size_t)(rowbase + row) * 1024 + k);
            *(float4*)&As[row * 64 + ((q ^ (row & 7)) << 3)] = v;
        }
        {
            int row = tid >> 3, q = tid & 7;
            float4 w = *(const float4*)(WcatT + (size_t)(nbase + row) * KCAT + kbase + q * 8);
            *(float4*)&Bs[row * 64 + ((q ^ (row & 7)) << 3)] = w;
        }
        __syncthreads();
        #pragma unroll
        for (int ks2 = 0; ks2 < 2; ++ks2) {
            int q = ks2 * 4 + l4;
            bf16x8 a[2], bb;
            #pragma unroll
            for (int fm = 0; fm < 2; ++fm) {
                int ar = wm + fm * 16 + l15;
                a[fm] = *(const bf16x8*)&As[ar * 64 + ((q ^ (ar & 7)) << 3)];
            }
            {
                int br = wn + l15;
                bb = *(const bf16x8*)&Bs[br * 64 + ((q ^ (br & 7)) << 3)];
            }
            #pragma unroll
            for (int fm = 0; fm < 2; ++fm)
                acc[fm] = __builtin_amdgcn_mfma_f32_16x16x32_bf16(a[fm], bb, acc[fm], 0, 0, 0);
        }
        __syncthreads();
    }
    float* zp = zpart + (size_t)ksb * B * H4;
    #pragma unroll
    for (int fm = 0; fm < 2; ++fm)
        #pragma unroll
        for (int j = 0; j < 4; ++j) {
            int m = rowbase + wm + fm * 16 + l4 * 4 + j;
            zp[(size_t)m * H4 + nbase + wn + l15] = acc[fm][j];
        }
}

// ---------- fused cell + attention. grid (B, 4), 256 thr ----------
// r13 body with ONE isolated change: context loads batched 25+24 deep (2 latency
// rounds instead of 7). Accumulation order over l unchanged -> bit-identical.
__global__ __launch_bounds__(256) void k_step4(
    const float* __restrict__ zpart, const float* __restrict__ wpart,
    const float* __restrict__ bias,
    const float* __restrict__ cb_cur, float* __restrict__ cb_nxt,
    unsigned short* __restrict__ Abuf,
    const unsigned short* __restrict__ Xb, const float* __restrict__ fscore,
    const float* __restrict__ w_a_h,
    float* __restrict__ out_h, float* __restrict__ out_m, float* __restrict__ out_a,
    int t_next) {
    __shared__ float red[8];
    __shared__ float sal[200];
    __shared__ float sp2[4][64][2];
    int b = blockIdx.x, quarter = blockIdx.y, tid = threadIdx.x;
    int lane = tid & 63, wid = tid >> 6;
    int n0 = tid * 2;
    float hp;
    if (t_next > 0) {
        const float* wp = wpart + ((size_t)b * T + (t_next - 1)) * H4;
        float2 z[4];
        #pragma unroll
        for (int g = 0; g < 4; ++g) {
            float2 bz = *(const float2*)(bias + g * H + n0);
            float2 wz = *(const float2*)(wp + g * H + n0);
            z[g].x = bz.x + wz.x; z[g].y = bz.y + wz.y;
        }
        #pragma unroll
        for (int ks = 0; ks < KS; ++ks) {
            const float* zp = zpart + ((size_t)ks * B + b) * H4;
            #pragma unroll
            for (int g = 0; g < 4; ++g) {
                float2 v = *(const float2*)(zp + g * H + n0);
                z[g].x += v.x; z[g].y += v.y;
            }
        }
        float2 cv = *(const float2*)(cb_cur + (size_t)b * H + n0);
        float cnx = sigf(z[1].x) * cv.x + sigf(z[0].x) * tanhf(z[2].x);
        float cny = sigf(z[1].y) * cv.y + sigf(z[0].y) * tanhf(z[2].y);
        float hnx = sigf(z[3].x) * tanhf(cnx);
        float hny = sigf(z[3].y) * tanhf(cny);
        if (quarter == 0) {
            int tp = t_next - 1;
            *(float2*)(cb_nxt + (size_t)b * H + n0) = make_float2(cnx, cny);
            *(float2*)(out_m + ((size_t)tp * B + b) * H + n0) = make_float2(cnx, cny);
            *(float2*)(out_h + ((size_t)b * T + tp) * H + n0) = make_float2(hnx, hny);
            ushort2 hu; hu.x = f2bf(hnx); hu.y = f2bf(hny);
            *(ushort2*)(Abuf + (size_t)b * 1024 + 512 + n0) = hu;
        }
        hp = hnx * w_a_h[n0] + hny * w_a_h[n0 + 1];
    } else {
        ushort2 hu = *(const ushort2*)(Abuf + (size_t)b * 1024 + 512 + n0);
        hp = bf2f(hu.x) * w_a_h[n0] + bf2f(hu.y) * w_a_h[n0 + 1];
    }
    if (t_next >= T) return;

    float s = wred_sum(hp);
    if (lane == 0) red[wid] = s;
    __syncthreads();
    float hs = red[0] + red[1] + red[2] + red[3];
    float scv = (tid < L) ? tanhf(hs + fscore[b * L + tid]) : 0.f;
    float ex = (tid < L) ? expf(scv) : 0.f;   // bounded: scv in [-1,1]
    float es = wred_sum(ex);
    if (lane == 0) red[4 + wid] = es;
    __syncthreads();
    float denom = red[4] + red[5] + red[6] + red[7];
    float al = ex / denom;
    if (tid < L) {
        sal[tid] = al;
        if (quarter == 0) out_a[((size_t)b * T + t_next) * L + tid] = al;
    }
    __syncthreads();

    // context: quarter owns uint cols quarter*64 + (tid&63); l-group of 49, 25+24 deep
    int fi = tid & 63, lg = tid >> 6;
    const unsigned* xb32 = (const unsigned*)(Xb + (size_t)b * L * F2) + quarter * 64 + fi;
    int l0 = lg * 49;
    float a0 = 0.f, a1 = 0.f;
    {
        unsigned u[25];
        #pragma unroll
        for (int j = 0; j < 25; ++j) u[j] = xb32[(size_t)(l0 + j) * 256];
        #pragma unroll
        for (int j = 0; j < 25; ++j) {
            float w = sal[l0 + j];
            a0 += bf2f((unsigned short)(u[j] & 0xFFFF)) * w;
            a1 += bf2f((unsigned short)(u[j] >> 16)) * w;
        }
    }
    {
        unsigned u[24];
        #pragma unroll
        for (int j = 0; j < 24; ++j) u[j] = xb32[(size_t)(l0 + 25 + j) * 256];
        #pragma unroll
        for (int j = 0; j < 24; ++j) {
            float w = sal[l0 + 25 + j];
            a0 += bf2f((unsigned short)(u[j] & 0xFFFF)) * w;
            a1 += bf2f((unsigned short)(u[j] >> 16)) * w;
        }
    }
    sp2[lg][fi][0] = a0; sp2[lg][fi][1] = a1;
    __syncthreads();
    if (tid < 64) {
        ushort2 cu;
        cu.x = f2bf(sp2[0][tid][0] + sp2[1][tid][0] + sp2[2][tid][0] + sp2[3][tid][0]);
        cu.y = f2bf(sp2[0][tid][1] + sp2[1][tid][1] + sp2[2][tid][1] + sp2[3][tid][1]);
        *(ushort2*)(Abuf + (size_t)b * 1024 + (quarter * 64 + tid) * 2) = cu;
    }
}

extern "C" void kernel_launch(void* const* d_in, const int* in_sizes, int n_in,
                              void* d_out, int out_size, void* d_ws, size_t ws_size,
                              hipStream_t stream) {
    (void)in_sizes; (void)n_in; (void)out_size; (void)ws_size;
    const float* X     = (const float*)d_in[0];
    const float* word  = (const float*)d_in[1];
    const float* w_h   = (const float*)d_in[2];
    const float* b_h   = (const float*)d_in[3];
    const float* w_c   = (const float*)d_in[4];
    const float* b_c   = (const float*)d_in[5];
    const float* w_a_h = (const float*)d_in[6];
    const float* w_a   = (const float*)d_in[7];
    const float* b_a   = (const float*)d_in[8];
    const float* k_w   = (const float*)d_in[9];
    const float* r_w   = (const float*)d_in[10];
    const float* bias  = (const float*)d_in[11];

    float* out_h = (float*)d_out;
    float* out_m = out_h + (size_t)B * T * H;
    float* out_a = out_m + (size_t)T * B * H;

    // ws layout — ~71 MB
    char* p = (char*)d_ws;
    unsigned short* Xb    = (unsigned short*)p; p += (size_t)B * L * F2 * 2;
    unsigned short* WcatT = (unsigned short*)p; p += (size_t)H4 * KCAT * 2;
    unsigned short* wT    = (unsigned short*)p; p += (size_t)H4 * 256 * 2;
    unsigned short* wiT   = (unsigned short*)p; p += (size_t)1024 * 512 * 2;
    unsigned short* fmb   = (unsigned short*)p; p += (size_t)B * F2 * 2;
    unsigned short* Abuf  = (unsigned short*)p; p += (size_t)B * 1024 * 2;
    float* fscore = (float*)p; p += (size_t)B * L * 4;
    float* cb0    = (float*)p; p += (size_t)B * H * 4;
    float* cb1    = (float*)p; p += (size_t)B * H * 4;
    float* zpart  = (float*)p; p += (size_t)KS * B * H4 * 4;
    float* wpart  = (float*)p; p += (size_t)B * T * H4 * 4;
    // fmpart (B*7*512 fp32 = 1.84 MB) aliases zpart (4.19 MB); lifetimes disjoint
    float* fmpart = zpart;

    k_prep2<<<dim3(B, 7), 256, 0, stream>>>(X, w_a, b_a, Xb, fscore, fmpart);
    k_mred<<<B, 256, 0, stream>>>(fmpart, fmb);
    k_trW<<<dim3(16, 32, 3), 256, 0, stream>>>(k_w, r_w, WcatT, wT);
    k_trI<<<dim3(16, 8, 2), 256, 0, stream>>>(w_h, w_c, wiT);
    k_wgemm<<<dim3(16, 32), 256, 0, stream>>>(word, wT, wpart);
    k_init_gemm<<<8, 256, 0, stream>>>(fmb, wiT, b_h, b_c, Abuf, cb0);

    // c_t lives in cb[t&1]; init wrote cb0 (= c_0)
    float* cb[2] = {cb0, cb1};
    k_step4<<<dim3(B, 4), 256, 0, stream>>>(zpart, wpart, bias, cb0, cb1, Abuf, Xb,
                                            fscore, w_a_h, out_h, out_m, out_a, 0);
    for (int t = 0; t < T; ++t) {
        k_gemm32<<<512, 256, 0, stream>>>(Abuf, WcatT, zpart);
        k_step4<<<dim3(B, 4), 256, 0, stream>>>(zpart, wpart, bias, cb[t & 1], cb[(t + 1) & 1],
                                                Abuf, Xb, fscore, w_a_h,
                                                out_h, out_m, out_a, t + 1);
    }
}

// Round 15
// 457.881 us; speedup vs baseline: 8.3752x; 1.0039x over previous
//
#include <hip/hip_runtime.h>
#include <math.h>

#define B  128
#define L  196
#define F2 512
#define T  32
#define D  256
#define H  512
#define H4 2048
#define KCAT 1024     // ctx(512) + h(512); word part precomputed
#define KS 4
#define KCHUNK 256    // KCAT/KS

typedef __attribute__((ext_vector_type(8))) short bf16x8;
typedef __attribute__((ext_vector_type(4))) float f32x4;

__device__ __forceinline__ float sigf(float x) { return 1.0f / (1.0f + expf(-x)); }
__device__ __forceinline__ unsigned short f2bf(float x) {
    unsigned u = __float_as_uint(x);
    u += 0x7FFF + ((u >> 16) & 1);
    return (unsigned short)(u >> 16);
}
__device__ __forceinline__ float bf2f(unsigned short s) {
    return __uint_as_float(((unsigned)s) << 16);
}
__device__ __forceinline__ float wred_sum(float v) {
    for (int o = 32; o > 0; o >>= 1) v += __shfl_down(v, o);
    return v;
}

// ---------- setup ----------

__global__ void k_prep2(const float* __restrict__ X, const float* __restrict__ w_a,
                        const float* __restrict__ b_a, unsigned short* __restrict__ Xb,
                        float* __restrict__ fscore, float* __restrict__ fmpart) {
    __shared__ float sp[8][512];
    int b = blockIdx.x, g = blockIdx.y, tid = threadIdx.x;
    int rowi = tid >> 5, lane32 = tid & 31;
    int f0 = tid * 2;
    float2 acc = make_float2(0.f, 0.f);
    for (int s = 0; s < 4; ++s) {
        int li = s * 8 + rowi;
        float4 part[4];
        if (li < 28) {
            size_t row = (size_t)b * L + g * 28 + li;
            const float* src = X + row * F2;
            unsigned short* dst = Xb + row * F2;
            float sc = 0.f;
            #pragma unroll
            for (int j = 0; j < 4; ++j) {
                int f = j * 128 + lane32 * 4;
                float4 v = *(const float4*)(src + f);
                float4 w = *(const float4*)(w_a + f);
                sc += v.x * w.x + v.y * w.y + v.z * w.z + v.w * w.w;
                part[j] = v;
                ushort4 u;
                u.x = f2bf(v.x); u.y = f2bf(v.y); u.z = f2bf(v.z); u.w = f2bf(v.w);
                *(ushort4*)(dst + f) = u;
            }
            for (int o = 16; o > 0; o >>= 1) sc += __shfl_down(sc, o, 32);
            if (lane32 == 0) fscore[row] = sc + b_a[0];
        } else {
            #pragma unroll
            for (int j = 0; j < 4; ++j) part[j] = make_float4(0.f, 0.f, 0.f, 0.f);
        }
        __syncthreads();
        #pragma unroll
        for (int j = 0; j < 4; ++j)
            *(float4*)&sp[rowi][j * 128 + lane32 * 4] = part[j];
        __syncthreads();
        #pragma unroll
        for (int r = 0; r < 8; ++r) { acc.x += sp[r][f0]; acc.y += sp[r][f0 + 1]; }
    }
    *(float2*)&fmpart[((size_t)b * 7 + g) * 512 + f0] = acc;
}

__global__ void k_mred(const float* __restrict__ fmpart, unsigned short* __restrict__ fmb) {
    int b = blockIdx.x, tid = threadIdx.x;
    int f0 = tid * 2;
    float2 acc = make_float2(0.f, 0.f);
    #pragma unroll
    for (int g = 0; g < 7; ++g) {
        float2 v = *(const float2*)&fmpart[((size_t)b * 7 + g) * 512 + f0];
        acc.x += v.x; acc.y += v.y;
    }
    ushort2 u; u.x = f2bf(acc.x * (1.0f / L)); u.y = f2bf(acc.y * (1.0f / L));
    *(ushort2*)(fmb + (size_t)b * F2 + f0) = u;
}

// all 5 transpose-cast jobs in one kernel. grid (16, 32, 5), 256 thr.
// job0: k_w[256:768]->WcatT cols 0..511; job1: r_w->WcatT cols 512..1023;
// job2: k_w[0:256]->wT [2048][256] (x<8); job3: w_h->wiT[0:512] (y<8);
// job4: w_c->wiT[512:1024] (y<8). Bodies byte-identical to the verified r13/r14 ones.
__global__ void k_trAll(const float* __restrict__ k_w, const float* __restrict__ r_w,
                        const float* __restrict__ w_h, const float* __restrict__ w_c,
                        unsigned short* __restrict__ WcatT, unsigned short* __restrict__ wT,
                        unsigned short* __restrict__ wiT) {
    int job = blockIdx.z;
    if (job == 2 && blockIdx.x >= 8) return;
    if (job >= 3 && blockIdx.y >= 8) return;
    const float* src; unsigned short* dstBase; int srcLD, dstLD, colOff;
    if (job == 0)      { src = k_w + (size_t)256 * H4; dstBase = WcatT; srcLD = H4;  dstLD = KCAT; colOff = 0; }
    else if (job == 1) { src = r_w;  dstBase = WcatT;                   srcLD = H4;  dstLD = KCAT; colOff = 512; }
    else if (job == 2) { src = k_w;  dstBase = wT;                      srcLD = H4;  dstLD = 256;  colOff = 0; }
    else if (job == 3) { src = w_h;  dstBase = wiT;                     srcLD = 512; dstLD = 512;  colOff = 0; }
    else               { src = w_c;  dstBase = wiT + (size_t)512 * 512; srcLD = 512; dstLD = 512;  colOff = 0; }
    __shared__ float Ls[32][65];
    int r0 = blockIdx.x * 32, c0 = blockIdx.y * 64;
    int tid = threadIdx.x;
    int r = tid >> 3, c8 = (tid & 7) * 8;
    const float* s = src + (size_t)(r0 + r) * srcLD + c0 + c8;
    #pragma unroll
    for (int j = 0; j < 8; ++j) Ls[r][c8 + j] = s[j];
    __syncthreads();
    int cc = tid >> 2, q = tid & 3;
    unsigned short tmp[8];
    #pragma unroll
    for (int j = 0; j < 8; ++j) tmp[j] = f2bf(Ls[q * 8 + j][cc]);
    *(float4*)(dstBase + (size_t)(c0 + cc) * dstLD + colOff + r0 + q * 8) = *(float4*)tmp;
}

// ---------- combined one-time GEMMs: z=0 wgemm (16x32 tiles), z=1 init_gemm (8 tiles) ----------
// Both bodies byte-identical to the verified r13/r14 kernels; merged to cut 1 node.
__global__ __launch_bounds__(256) void k_wi(
    const float* __restrict__ word,           // [4096][256] fp32
    const unsigned short* __restrict__ wT,    // [2048][256] bf16
    float* __restrict__ wpart,                // [4096][2048] fp32
    const unsigned short* __restrict__ A,     // fm_bf16 [128][512]
    const unsigned short* __restrict__ Bt,    // wiT [1024][512]
    const float* __restrict__ b_h, const float* __restrict__ b_c,
    unsigned short* __restrict__ Abuf0, float* __restrict__ cbuf) {
    __shared__ short As[128 * 64];
    __shared__ short Bs[128 * 64];
    int tid = threadIdx.x;
    int wave = tid >> 6, lane = tid & 63;
    int wm = (wave >> 1) * 64, wn = (wave & 1) * 64;
    int l15 = lane & 15, l4 = lane >> 4;

    f32x4 acc[4][4];
    #pragma unroll
    for (int i = 0; i < 4; ++i)
        #pragma unroll
        for (int j = 0; j < 4; ++j) acc[i][j] = (f32x4){0.f, 0.f, 0.f, 0.f};

    if (blockIdx.z == 1) {
        // ---- init-state GEMM: M=128, K=512, N=1024 ----
        if (blockIdx.x >= 8 || blockIdx.y != 0) return;
        int nbase = blockIdx.x * 128;
        for (int it = 0; it < 8; ++it) {
            int kbase = it * 64;
            #pragma unroll
            for (int ch = 0; ch < 4; ++ch) {
                int idx = ch * 256 + tid;
                int row = idx >> 3, q = idx & 7;
                int k = kbase + q * 8;
                float4 v = *(const float4*)(A + (size_t)row * 512 + k);
                *(float4*)&As[row * 64 + ((q ^ (row & 7)) << 3)] = v;
                float4 w = *(const float4*)(Bt + (size_t)(nbase + row) * 512 + k);
                *(float4*)&Bs[row * 64 + ((q ^ (row & 7)) << 3)] = w;
            }
            __syncthreads();
            #pragma unroll
            for (int ks = 0; ks < 2; ++ks) {
                bf16x8 a[4], b[4];
                #pragma unroll
                for (int f = 0; f < 4; ++f) {
                    int ar = wm + f * 16 + l15;
                    int q = ks * 4 + l4;
                    a[f] = *(const bf16x8*)&As[ar * 64 + ((q ^ (ar & 7)) << 3)];
                    int br = wn + f * 16 + l15;
                    b[f] = *(const bf16x8*)&Bs[br * 64 + ((q ^ (br & 7)) << 3)];
                }
                #pragma unroll
                for (int fm = 0; fm < 4; ++fm)
                    #pragma unroll
                    for (int fn = 0; fn < 4; ++fn)
                        acc[fm][fn] = __builtin_amdgcn_mfma_f32_16x16x32_bf16(a[fm], b[fn], acc[fm][fn], 0, 0, 0);
            }
            __syncthreads();
        }
        #pragma unroll
        for (int fm = 0; fm < 4; ++fm)
            #pragma unroll
            for (int j = 0; j < 4; ++j) {
                int m = wm + fm * 16 + l4 * 4 + j;
                #pragma unroll
                for (int fn = 0; fn < 4; ++fn) {
                    int gn = nbase + wn + fn * 16 + l15;
                    float v = acc[fm][fn][j];
                    if (gn < 512) Abuf0[(size_t)m * 1024 + 512 + gn] = f2bf(tanhf(v + b_h[gn]));
                    else          cbuf[(size_t)m * 512 + gn - 512] = tanhf(v + b_c[gn - 512]);
                }
            }
        return;
    }

    // ---- word GEMM: wpart = bf16(word) @ wT^T.  M=4096, K=256, N=2048 ----
    int nbase = blockIdx.x * 128;
    int mbase = blockIdx.y * 128;
    for (int it = 0; it < 4; ++it) {
        int kbase = it * 64;
        #pragma unroll
        for (int ch = 0; ch < 4; ++ch) {
            int idx = ch * 256 + tid;
            int row = idx >> 3, q = idx & 7;
            int k = kbase + q * 8;
            const float* ap = word + (size_t)(mbase + row) * 256 + k;
            float4 v0 = *(const float4*)ap;
            float4 v1 = *(const float4*)(ap + 4);
            unsigned short tmp[8];
            tmp[0] = f2bf(v0.x); tmp[1] = f2bf(v0.y); tmp[2] = f2bf(v0.z); tmp[3] = f2bf(v0.w);
            tmp[4] = f2bf(v1.x); tmp[5] = f2bf(v1.y); tmp[6] = f2bf(v1.z); tmp[7] = f2bf(v1.w);
            *(float4*)&As[row * 64 + ((q ^ (row & 7)) << 3)] = *(float4*)tmp;
            float4 w = *(const float4*)(wT + (size_t)(nbase + row) * 256 + k);
            *(float4*)&Bs[row * 64 + ((q ^ (row & 7)) << 3)] = w;
        }
        __syncthreads();
        #pragma unroll
        for (int ks = 0; ks < 2; ++ks) {
            bf16x8 a[4], b[4];
            #pragma unroll
            for (int f = 0; f < 4; ++f) {
                int ar = wm + f * 16 + l15;
                int q = ks * 4 + l4;
                a[f] = *(const bf16x8*)&As[ar * 64 + ((q ^ (ar & 7)) << 3)];
                int br = wn + f * 16 + l15;
                b[f] = *(const bf16x8*)&Bs[br * 64 + ((q ^ (br & 7)) << 3)];
            }
            #pragma unroll
            for (int fm = 0; fm < 4; ++fm)
                #pragma unroll
                for (int fn = 0; fn < 4; ++fn)
                    acc[fm][fn] = __builtin_amdgcn_mfma_f32_16x16x32_bf16(a[fm], b[fn], acc[fm][fn], 0, 0, 0);
        }
        __syncthreads();
    }
    #pragma unroll
    for (int fm = 0; fm < 4; ++fm)
        #pragma unroll
        for (int j = 0; j < 4; ++j) {
            int m = wm + fm * 16 + l4 * 4 + j;
            #pragma unroll
            for (int fn = 0; fn < 4; ++fn)
                wpart[(size_t)(mbase + m) * H4 + nbase + wn + fn * 16 + l15] = acc[fm][fn][j];
        }
}

// ---------- per-step gates GEMM: K=1024, 64x32 tiles, 512 blocks (byte-exact r13/r14) ----------
__global__ __launch_bounds__(256) void k_gemm32(
    const unsigned short* __restrict__ Abuf,
    const unsigned short* __restrict__ WcatT,  // [2048][1024]
    float* __restrict__ zpart) {
    __shared__ short As[64 * 64];
    __shared__ short Bs[32 * 64];
    int tid = threadIdx.x;
    int bid = blockIdx.x;
    int ksb = bid >> 7, rem = bid & 127;
    int rowbase = (rem >> 6) * 64, nbase = (rem & 63) * 32;
    int wave = tid >> 6, lane = tid & 63;
    int wm = (wave & 1) * 32, wn = (wave >> 1) * 16;
    int l15 = lane & 15, l4 = lane >> 4;

    f32x4 acc[2];
    acc[0] = (f32x4){0.f, 0.f, 0.f, 0.f};
    acc[1] = (f32x4){0.f, 0.f, 0.f, 0.f};

    for (int it = 0; it < KCHUNK / 64; ++it) {
        int kbase = ksb * KCHUNK + it * 64;
        #pragma unroll
        for (int p = 0; p < 2; ++p) {
            int idx = p * 256 + tid;
            int row = idx >> 3, q = idx & 7;
            int k = kbase + q * 8;
            float4 v = *(const float4*)(Abuf + (size_t)(rowbase + row) * 1024 + k);
            *(float4*)&As[row * 64 + ((q ^ (row & 7)) << 3)] = v;
        }
        {
            int row = tid >> 3, q = tid & 7;
            float4 w = *(const float4*)(WcatT + (size_t)(nbase + row) * KCAT + kbase + q * 8);
            *(float4*)&Bs[row * 64 + ((q ^ (row & 7)) << 3)] = w;
        }
        __syncthreads();
        #pragma unroll
        for (int ks2 = 0; ks2 < 2; ++ks2) {
            int q = ks2 * 4 + l4;
            bf16x8 a[2], bb;
            #pragma unroll
            for (int fm = 0; fm < 2; ++fm) {
                int ar = wm + fm * 16 + l15;
                a[fm] = *(const bf16x8*)&As[ar * 64 + ((q ^ (ar & 7)) << 3)];
            }
            {
                int br = wn + l15;
                bb = *(const bf16x8*)&Bs[br * 64 + ((q ^ (br & 7)) << 3)];
            }
            #pragma unroll
            for (int fm = 0; fm < 2; ++fm)
                acc[fm] = __builtin_amdgcn_mfma_f32_16x16x32_bf16(a[fm], bb, acc[fm], 0, 0, 0);
        }
        __syncthreads();
    }
    float* zp = zpart + (size_t)ksb * B * H4;
    #pragma unroll
    for (int fm = 0; fm < 2; ++fm)
        #pragma unroll
        for (int j = 0; j < 4; ++j) {
            int m = rowbase + wm + fm * 16 + l4 * 4 + j;
            zp[(size_t)m * H4 + nbase + wn + l15] = acc[fm][j];
        }
}

// ---------- fused cell + attention. grid (B, 4), 256 thr (byte-exact r14) ----------
__global__ __launch_bounds__(256) void k_step4(
    const float* __restrict__ zpart, const float* __restrict__ wpart,
    const float* __restrict__ bias,
    const float* __restrict__ cb_cur, float* __restrict__ cb_nxt,
    unsigned short* __restrict__ Abuf,
    const unsigned short* __restrict__ Xb, const float* __restrict__ fscore,
    const float* __restrict__ w_a_h,
    float* __restrict__ out_h, float* __restrict__ out_m, float* __restrict__ out_a,
    int t_next) {
    __shared__ float red[8];
    __shared__ float sal[200];
    __shared__ float sp2[4][64][2];
    int b = blockIdx.x, quarter = blockIdx.y, tid = threadIdx.x;
    int lane = tid & 63, wid = tid >> 6;
    int n0 = tid * 2;
    float hp;
    if (t_next > 0) {
        const float* wp = wpart + ((size_t)b * T + (t_next - 1)) * H4;
        float2 z[4];
        #pragma unroll
        for (int g = 0; g < 4; ++g) {
            float2 bz = *(const float2*)(bias + g * H + n0);
            float2 wz = *(const float2*)(wp + g * H + n0);
            z[g].x = bz.x + wz.x; z[g].y = bz.y + wz.y;
        }
        #pragma unroll
        for (int ks = 0; ks < KS; ++ks) {
            const float* zp = zpart + ((size_t)ks * B + b) * H4;
            #pragma unroll
            for (int g = 0; g < 4; ++g) {
                float2 v = *(const float2*)(zp + g * H + n0);
                z[g].x += v.x; z[g].y += v.y;
            }
        }
        float2 cv = *(const float2*)(cb_cur + (size_t)b * H + n0);
        float cnx = sigf(z[1].x) * cv.x + sigf(z[0].x) * tanhf(z[2].x);
        float cny = sigf(z[1].y) * cv.y + sigf(z[0].y) * tanhf(z[2].y);
        float hnx = sigf(z[3].x) * tanhf(cnx);
        float hny = sigf(z[3].y) * tanhf(cny);
        if (quarter == 0) {
            int tp = t_next - 1;
            *(float2*)(cb_nxt + (size_t)b * H + n0) = make_float2(cnx, cny);
            *(float2*)(out_m + ((size_t)tp * B + b) * H + n0) = make_float2(cnx, cny);
            *(float2*)(out_h + ((size_t)b * T + tp) * H + n0) = make_float2(hnx, hny);
            ushort2 hu; hu.x = f2bf(hnx); hu.y = f2bf(hny);
            *(ushort2*)(Abuf + (size_t)b * 1024 + 512 + n0) = hu;
        }
        hp = hnx * w_a_h[n0] + hny * w_a_h[n0 + 1];
    } else {
        ushort2 hu = *(const ushort2*)(Abuf + (size_t)b * 1024 + 512 + n0);
        hp = bf2f(hu.x) * w_a_h[n0] + bf2f(hu.y) * w_a_h[n0 + 1];
    }
    if (t_next >= T) return;

    float s = wred_sum(hp);
    if (lane == 0) red[wid] = s;
    __syncthreads();
    float hs = red[0] + red[1] + red[2] + red[3];
    float scv = (tid < L) ? tanhf(hs + fscore[b * L + tid]) : 0.f;
    float ex = (tid < L) ? expf(scv) : 0.f;   // bounded: scv in [-1,1]
    float es = wred_sum(ex);
    if (lane == 0) red[4 + wid] = es;
    __syncthreads();
    float denom = red[4] + red[5] + red[6] + red[7];
    float al = ex / denom;
    if (tid < L) {
        sal[tid] = al;
        if (quarter == 0) out_a[((size_t)b * T + t_next) * L + tid] = al;
    }
    __syncthreads();

    int fi = tid & 63, lg = tid >> 6;
    const unsigned* xb32 = (const unsigned*)(Xb + (size_t)b * L * F2) + quarter * 64 + fi;
    int l0 = lg * 49;
    float a0 = 0.f, a1 = 0.f;
    {
        unsigned u[25];
        #pragma unroll
        for (int j = 0; j < 25; ++j) u[j] = xb32[(size_t)(l0 + j) * 256];
        #pragma unroll
        for (int j = 0; j < 25; ++j) {
            float w = sal[l0 + j];
            a0 += bf2f((unsigned short)(u[j] & 0xFFFF)) * w;
            a1 += bf2f((unsigned short)(u[j] >> 16)) * w;
        }
    }
    {
        unsigned u[24];
        #pragma unroll
        for (int j = 0; j < 24; ++j) u[j] = xb32[(size_t)(l0 + 25 + j) * 256];
        #pragma unroll
        for (int j = 0; j < 24; ++j) {
            float w = sal[l0 + 25 + j];
            a0 += bf2f((unsigned short)(u[j] & 0xFFFF)) * w;
            a1 += bf2f((unsigned short)(u[j] >> 16)) * w;
        }
    }
    sp2[lg][fi][0] = a0; sp2[lg][fi][1] = a1;
    __syncthreads();
    if (tid < 64) {
        ushort2 cu;
        cu.x = f2bf(sp2[0][tid][0] + sp2[1][tid][0] + sp2[2][tid][0] + sp2[3][tid][0]);
        cu.y = f2bf(sp2[0][tid][1] + sp2[1][tid][1] + sp2[2][tid][1] + sp2[3][tid][1]);
        *(ushort2*)(Abuf + (size_t)b * 1024 + (quarter * 64 + tid) * 2) = cu;
    }
}

extern "C" void kernel_launch(void* const* d_in, const int* in_sizes, int n_in,
                              void* d_out, int out_size, void* d_ws, size_t ws_size,
                              hipStream_t stream) {
    (void)in_sizes; (void)n_in; (void)out_size; (void)ws_size;
    const float* X     = (const float*)d_in[0];
    const float* word  = (const float*)d_in[1];
    const float* w_h   = (const float*)d_in[2];
    const float* b_h   = (const float*)d_in[3];
    const float* w_c   = (const float*)d_in[4];
    const float* b_c   = (const float*)d_in[5];
    const float* w_a_h = (const float*)d_in[6];
    const float* w_a   = (const float*)d_in[7];
    const float* b_a   = (const float*)d_in[8];
    const float* k_w   = (const float*)d_in[9];
    const float* r_w   = (const float*)d_in[10];
    const float* bias  = (const float*)d_in[11];

    float* out_h = (float*)d_out;
    float* out_m = out_h + (size_t)B * T * H;
    float* out_a = out_m + (size_t)T * B * H;

    // ws layout — ~71 MB
    char* p = (char*)d_ws;
    unsigned short* Xb    = (unsigned short*)p; p += (size_t)B * L * F2 * 2;
    unsigned short* WcatT = (unsigned short*)p; p += (size_t)H4 * KCAT * 2;
    unsigned short* wT    = (unsigned short*)p; p += (size_t)H4 * 256 * 2;
    unsigned short* wiT   = (unsigned short*)p; p += (size_t)1024 * 512 * 2;
    unsigned short* fmb   = (unsigned short*)p; p += (size_t)B * F2 * 2;
    unsigned short* Abuf  = (unsigned short*)p; p += (size_t)B * 1024 * 2;
    float* fscore = (float*)p; p += (size_t)B * L * 4;
    float* cb0    = (float*)p; p += (size_t)B * H * 4;
    float* cb1    = (float*)p; p += (size_t)B * H * 4;
    float* zpart  = (float*)p; p += (size_t)KS * B * H4 * 4;
    float* wpart  = (float*)p; p += (size_t)B * T * H4 * 4;
    // fmpart (B*7*512 fp32 = 1.84 MB) aliases zpart (4.19 MB); lifetimes disjoint
    float* fmpart = zpart;

    k_prep2<<<dim3(B, 7), 256, 0, stream>>>(X, w_a, b_a, Xb, fscore, fmpart);
    k_mred<<<B, 256, 0, stream>>>(fmpart, fmb);
    k_trAll<<<dim3(16, 32, 5), 256, 0, stream>>>(k_w, r_w, w_h, w_c, WcatT, wT, wiT);
    k_wi<<<dim3(16, 32, 2), 256, 0, stream>>>(word, wT, wpart, fmb, wiT, b_h, b_c, Abuf, cb0);

    // c_t lives in cb[t&1]; k_wi (z=1) wrote cb0 (= c_0)
    float* cb[2] = {cb0, cb1};
    k_step4<<<dim3(B, 4), 256, 0, stream>>>(zpart, wpart, bias, cb0, cb1, Abuf, Xb,
                                            fscore, w_a_h, out_h, out_m, out_a, 0);
    for (int t = 0; t < T; ++t) {
        k_gemm32<<<512, 256, 0, stream>>>(Abuf, WcatT, zpart);
        k_step4<<<dim3(B, 4), 256, 0, stream>>>(zpart, wpart, bias, cb[t & 1], cb[(t + 1) & 1],
                                                Abuf, Xb, fscore, w_a_h,
                                                out_h, out_m, out_a, t + 1);
    }
}